// Round 1
// baseline (483.327 us; speedup 1.0000x reference)
//
#include <hip/hip_runtime.h>
#include <hip/hip_bf16.h>
#include <math.h>

// Problem constants
static constexpr int kB = 8;
static constexpr int kH = 8;
static constexpr int kL = 512;
static constexpr int kD = 512;
static constexpr int kDH = 64;     // D/H
static constexpr int kBH = 64;     // B*H
static constexpr int kROWS = kBH * kL;  // 32768

__device__ __forceinline__ float gelu_exact(float v) {
    return 0.5f * v * (1.0f + erff(v * 0.70710678118654752440f));
}

// ---------------------------------------------------------------------------
// K1: q = xh@W1^T + b1, k = xh@W2^T + b2.   grid = B*L blocks, 256 thr
// ---------------------------------------------------------------------------
__global__ __launch_bounds__(256) void k_qk(const float* __restrict__ x,
        const float* __restrict__ W1, const float* __restrict__ b1,
        const float* __restrict__ W2, const float* __restrict__ b2,
        float* __restrict__ q, float* __restrict__ k) {
    int bl = blockIdx.x;               // b*L + l
    int b = bl >> 9, l = bl & (kL - 1);
    __shared__ float xs[kD];
    int tid = threadIdx.x;
    xs[tid]       = x[bl * kD + tid];
    xs[tid + 256] = x[bl * kD + tid + 256];
    __syncthreads();
    #pragma unroll
    for (int r = 0; r < 2; ++r) {
        int idx = tid + r * 256;       // h*64 + d
        int h = idx >> 6, d = idx & 63;
        float qa = b1[d], ka = b2[d];
        const float* xh = &xs[h * 64];
        const float* w1 = &W1[d * 64];
        const float* w2 = &W2[d * 64];
        #pragma unroll 8
        for (int dd = 0; dd < 64; ++dd) {
            float xv = xh[dd];
            qa = fmaf(xv, w1[dd], qa);
            ka = fmaf(xv, w2[dd], ka);
        }
        int o = ((b * kH + h) * kL + l) * kDH + d;
        q[o] = qa;
        k[o] = ka;
    }
}

// ---------------------------------------------------------------------------
// K2: adj = gelu(q @ k^T) per (b,h).  64x64 tile per block, 4x4 per thread.
// grid = B*H*8*8 = 4096
// ---------------------------------------------------------------------------
__global__ __launch_bounds__(256) void k_adj(const float* __restrict__ q,
        const float* __restrict__ k, float* __restrict__ adj) {
    int blk = blockIdx.x;
    int bh = blk >> 6;
    int it = (blk >> 3) & 7, jt = blk & 7;
    __shared__ float qs[64][65];
    __shared__ float ks[64][65];
    int tid = threadIdx.x;
    const float* qb = q + (bh * kL + it * 64) * kDH;
    const float* kb = k + (bh * kL + jt * 64) * kDH;
    #pragma unroll
    for (int r = 0; r < 16; ++r) {
        int e = tid + r * 256;
        int row = e >> 6, col = e & 63;
        qs[row][col] = qb[row * 64 + col];
        ks[row][col] = kb[row * 64 + col];
    }
    __syncthreads();
    int ty = tid >> 4, tx = tid & 15;
    float acc[4][4] = {};
    #pragma unroll 4
    for (int d = 0; d < 64; ++d) {
        float qa[4], kv[4];
        #pragma unroll
        for (int a = 0; a < 4; ++a) qa[a] = qs[ty * 4 + a][d];
        #pragma unroll
        for (int c = 0; c < 4; ++c) kv[c] = ks[tx * 4 + c][d];
        #pragma unroll
        for (int a = 0; a < 4; ++a)
            #pragma unroll
            for (int c = 0; c < 4; ++c)
                acc[a][c] = fmaf(qa[a], kv[c], acc[a][c]);
    }
    #pragma unroll
    for (int a = 0; a < 4; ++a)
        #pragma unroll
        for (int c = 0; c < 4; ++c) {
            float v = acc[a][c];
            adj[(bh * kL + it * 64 + ty * 4 + a) * kL + jt * 64 + tx * 4 + c] =
                gelu_exact(v);
        }
}

// ---------------------------------------------------------------------------
// K3: per-row (one wave): exact 256th-smallest via bitwise radix select,
// threshold, write back, logits = row @ Wg^T, softmax-3, stable top-p,
// gates/sp/entropy out.   grid = ROWS/4 blocks of 256 (4 waves)
// ---------------------------------------------------------------------------
__global__ __launch_bounds__(256) void k_select(float* __restrict__ adj,
        const float* __restrict__ Wg, float* __restrict__ gbuf,
        float* __restrict__ spbuf, float* __restrict__ entbuf) {
    int tid = threadIdx.x;
    int wave = tid >> 6, lane = tid & 63;
    int row = blockIdx.x * 4 + wave;
    float* arow = adj + (size_t)row * kL;

    float v[8];
    unsigned key[8];
    #pragma unroll
    for (int t = 0; t < 8; ++t) {
        v[t] = arow[t * 64 + lane];
        unsigned u = __float_as_uint(v[t]);
        key[t] = (u & 0x80000000u) ? ~u : (u | 0x80000000u);
    }
    // exact k-th smallest (k = 255, 0-indexed) via MSB-first bit select
    unsigned prefix = 0;
    unsigned act = 0xFFu;
    int kk = 255;
    for (int bit = 31; bit >= 0; --bit) {
        int c = 0;
        #pragma unroll
        for (int t = 0; t < 8; ++t)
            if (((act >> t) & 1u) && !((key[t] >> bit) & 1u)) ++c;
        #pragma unroll
        for (int off = 1; off < 64; off <<= 1) c += __shfl_xor(c, off);
        if (kk < c) {
            #pragma unroll
            for (int t = 0; t < 8; ++t)
                if ((key[t] >> bit) & 1u) act &= ~(1u << t);
        } else {
            kk -= c;
            prefix |= (1u << bit);
            #pragma unroll
            for (int t = 0; t < 8; ++t)
                if (!((key[t] >> bit) & 1u)) act &= ~(1u << t);
        }
    }
    float thr = (prefix & 0x80000000u) ? __uint_as_float(prefix ^ 0x80000000u)
                                       : __uint_as_float(~prefix);
    // threshold + logits
    float l0 = 0.f, l1 = 0.f, l2 = 0.f;
    #pragma unroll
    for (int t = 0; t < 8; ++t) {
        float nv = (v[t] > thr) ? v[t] : 0.0f;
        arow[t * 64 + lane] = nv;
        int j = t * 64 + lane;
        l0 = fmaf(nv, Wg[j], l0);
        l1 = fmaf(nv, Wg[kL + j], l1);
        l2 = fmaf(nv, Wg[2 * kL + j], l2);
    }
    #pragma unroll
    for (int off = 1; off < 64; off <<= 1) {
        l0 += __shfl_xor(l0, off);
        l1 += __shfl_xor(l1, off);
        l2 += __shfl_xor(l2, off);
    }
    if (lane == 0) {
        float m = fmaxf(l0, fmaxf(l1, l2));
        float e0 = expf(l0 - m), e1 = expf(l1 - m), e2 = expf(l2 - m);
        float s = e0 + e1 + e2;
        float p[3] = {e0 / s, e1 / s, e2 / s};
        // stable argsort of -p (descending p, ties -> lower index)
        int o0, o1, o2;
        if (p[0] >= p[1] && p[0] >= p[2]) o0 = 0;
        else if (p[1] >= p[2]) o0 = 1;
        else o0 = 2;
        int r0 = (o0 == 0) ? 1 : 0;
        int r1 = (o0 == 2) ? 1 : 2;
        if (p[r0] >= p[r1]) { o1 = r0; o2 = r1; } else { o1 = r1; o2 = r0; }
        float sp0 = p[o0], sp1 = p[o1], sp2 = p[o2];
        float c0 = sp0, c1 = sp0 + sp1, c2 = c1 + sp2;
        bool m0 = c0 > 0.5f, m1 = c1 > 0.5f, m2 = c2 > 0.5f;
        int ti = m0 ? 0 : (m1 ? 1 : 2);
        bool mm0 = m0 && (ti != 0);
        bool mm1 = m1 && (ti != 1);
        bool mm2 = m2 && (ti != 2);
        float g[3] = {0.f, 0.f, 0.f};
        g[o0] = mm0 ? 0.f : 1.f;
        g[o1] = mm1 ? 0.f : 1.f;
        g[o2] = mm2 ? 0.f : 1.f;
        gbuf[row * 3 + 0] = g[0];
        gbuf[row * 3 + 1] = g[1];
        gbuf[row * 3 + 2] = g[2];
        spbuf[row * 3 + 0] = mm0 ? 0.f : sp0;
        spbuf[row * 3 + 1] = mm1 ? 0.f : sp1;
        spbuf[row * 3 + 2] = mm2 ? 0.f : sp2;
        entbuf[row] = p[0] * logf(p[0] + 1e-10f) +
                      p[1] * logf(p[1] + 1e-10f) +
                      p[2] * logf(p[2] + 1e-10f);
    }
}

// ---------------------------------------------------------------------------
// K4: xp = x @ Wp^T + bp.  x as (B*L, D) GEMM.  grid = 64*8 = 512 blocks
// ---------------------------------------------------------------------------
__global__ __launch_bounds__(256) void k_xp(const float* __restrict__ x,
        const float* __restrict__ Wp, const float* __restrict__ bp,
        float* __restrict__ xp) {
    int it = blockIdx.x >> 3, jt = blockIdx.x & 7;
    __shared__ float xs[64][65];
    __shared__ float ws[64][65];
    int tid = threadIdx.x;
    int ty = tid >> 4, tx = tid & 15;
    float acc[4][4] = {};
    for (int kb = 0; kb < 8; ++kb) {
        #pragma unroll
        for (int r = 0; r < 16; ++r) {
            int e = tid + r * 256;
            int rr = e >> 6, cc = e & 63;
            xs[rr][cc] = x[(it * 64 + rr) * kD + kb * 64 + cc];
            ws[rr][cc] = Wp[(jt * 64 + rr) * kD + kb * 64 + cc];
        }
        __syncthreads();
        #pragma unroll 4
        for (int d = 0; d < 64; ++d) {
            float av[4], wv[4];
            #pragma unroll
            for (int a = 0; a < 4; ++a) av[a] = xs[ty * 4 + a][d];
            #pragma unroll
            for (int c = 0; c < 4; ++c) wv[c] = ws[tx * 4 + c][d];
            #pragma unroll
            for (int a = 0; a < 4; ++a)
                #pragma unroll
                for (int c = 0; c < 4; ++c)
                    acc[a][c] = fmaf(av[a], wv[c], acc[a][c]);
        }
        __syncthreads();
    }
    #pragma unroll
    for (int a = 0; a < 4; ++a)
        #pragma unroll
        for (int c = 0; c < 4; ++c)
            xp[(it * 64 + ty * 4 + a) * kD + jt * 64 + tx * 4 + c] =
                acc[a][c] + bp[jt * 64 + tx * 4 + c];
}

// ---------------------------------------------------------------------------
// K5: per-row mask build + masked softmax + L1 renorm, in place.
// grid = ROWS blocks of 256
// ---------------------------------------------------------------------------
__global__ __launch_bounds__(256) void k_msoft(float* __restrict__ adj,
        const float* __restrict__ masks, const float* __restrict__ gbuf) {
    int row = blockIdx.x;
    int i = row & (kL - 1);
    int tid = threadIdx.x;
    float g0 = gbuf[row * 3 + 0];
    float g1 = gbuf[row * 3 + 1];
    float g2 = gbuf[row * 3 + 2];
    const float* m0 = masks + (i * 3 + 0) * kL;
    const float* m1 = masks + (i * 3 + 1) * kL;
    const float* m2 = masks + (i * 3 + 2) * kL;
    float* arow = adj + (size_t)row * kL;

    float av[2];
    #pragma unroll
    for (int r = 0; r < 2; ++r) {
        int j = tid + r * 256;
        float mm = g0 * m0[j] + g1 * m1[j] + g2 * m2[j] + ((j == i) ? 1.0f : 0.0f);
        av[r] = arow[j] * mm;
    }
    __shared__ float red[256];
    // max
    red[tid] = fmaxf(av[0], av[1]);
    __syncthreads();
    for (int s = 128; s > 0; s >>= 1) {
        if (tid < s) red[tid] = fmaxf(red[tid], red[tid + s]);
        __syncthreads();
    }
    float mx = red[0];
    __syncthreads();
    float e0 = expf(av[0] - mx), e1 = expf(av[1] - mx);
    red[tid] = e0 + e1;
    __syncthreads();
    for (int s = 128; s > 0; s >>= 1) {
        if (tid < s) red[tid] += red[tid + s];
        __syncthreads();
    }
    float ssum = red[0];
    __syncthreads();
    float p0 = e0 / ssum, p1 = e1 / ssum;
    red[tid] = fabsf(p0) + fabsf(p1);
    __syncthreads();
    for (int s = 128; s > 0; s >>= 1) {
        if (tid < s) red[tid] += red[tid + s];
        __syncthreads();
    }
    float s2 = fmaxf(red[0], 1e-12f);
    arow[tid] = p0 / s2;
    arow[tid + 256] = p1 / s2;
}

// ---------------------------------------------------------------------------
// K6: out[b,i,h,d] = sum_j adjn[bh,i,j] * xp[b,j,h*64+d].
// grid = B*H*8 = 512 blocks, 64x64 tile, K=512 in chunks of 64.
// ---------------------------------------------------------------------------
__global__ __launch_bounds__(256) void k_out(const float* __restrict__ adj,
        const float* __restrict__ xp, float* __restrict__ out) {
    int blk = blockIdx.x;
    int bh = blk >> 3;
    int it = blk & 7;
    int b = bh >> 3, h = bh & 7;
    __shared__ float as_[64][65];
    __shared__ float xs[64][65];
    int tid = threadIdx.x;
    int ty = tid >> 4, tx = tid & 15;
    float acc[4][4] = {};
    for (int kb = 0; kb < 8; ++kb) {
        #pragma unroll
        for (int r = 0; r < 16; ++r) {
            int e = tid + r * 256;
            int rr = e >> 6, cc = e & 63;
            as_[rr][cc] = adj[((size_t)bh * kL + it * 64 + rr) * kL + kb * 64 + cc];
            xs[rr][cc] = xp[((size_t)b * kL + kb * 64 + rr) * kD + h * 64 + cc];
        }
        __syncthreads();
        #pragma unroll 4
        for (int d = 0; d < 64; ++d) {
            float av[4], xv[4];
            #pragma unroll
            for (int a = 0; a < 4; ++a) av[a] = as_[ty * 4 + a][d];
            #pragma unroll
            for (int c = 0; c < 4; ++c) xv[c] = xs[d][tx * 4 + c];
            #pragma unroll
            for (int a = 0; a < 4; ++a)
                #pragma unroll
                for (int c = 0; c < 4; ++c)
                    acc[a][c] = fmaf(av[a], xv[c], acc[a][c]);
        }
        __syncthreads();
    }
    #pragma unroll
    for (int a = 0; a < 4; ++a)
        #pragma unroll
        for (int c = 0; c < 4; ++c)
            out[((size_t)b * kL + it * 64 + ty * 4 + a) * kD + h * 64 + tx * 4 + c] =
                acc[a][c];
}

// ---------------------------------------------------------------------------
// K7: finalize loss (single block, deterministic reductions)
// ---------------------------------------------------------------------------
__global__ __launch_bounds__(1024) void k_loss(const float* __restrict__ spbuf,
        const float* __restrict__ entbuf, float* __restrict__ out_loss) {
    __shared__ float imps[kL * 3];
    __shared__ float red[1024];
    int tid = threadIdx.x;
    // imp[l, j] = sum over bh of spbuf[(bh*L + l)*3 + j]
    for (int idx = tid; idx < kL * 3; idx += 1024) {
        int l = idx / 3, j = idx - l * 3;
        float s = 0.f;
        for (int bh = 0; bh < kBH; ++bh)
            s += spbuf[(bh * kL + l) * 3 + j];
        imps[idx] = s;
    }
    // total entropy
    float es = 0.f;
    for (int idx = tid; idx < kROWS; idx += 1024) es += entbuf[idx];
    red[tid] = es;
    __syncthreads();
    for (int s = 512; s > 0; s >>= 1) {
        if (tid < s) red[tid] += red[tid + s];
        __syncthreads();
    }
    float ent_total = red[0];
    __syncthreads();
    // mean of imp
    float ms = 0.f;
    for (int idx = tid; idx < kL * 3; idx += 1024) ms += imps[idx];
    red[tid] = ms;
    __syncthreads();
    for (int s = 512; s > 0; s >>= 1) {
        if (tid < s) red[tid] += red[tid + s];
        __syncthreads();
    }
    float mean = red[0] / (float)(kL * 3);
    __syncthreads();
    // variance (ddof=1)
    float vs = 0.f;
    for (int idx = tid; idx < kL * 3; idx += 1024) {
        float d = imps[idx] - mean;
        vs += d * d;
    }
    red[tid] = vs;
    __syncthreads();
    for (int s = 512; s > 0; s >>= 1) {
        if (tid < s) red[tid] += red[tid + s];
        __syncthreads();
    }
    if (tid == 0) {
        float var = red[0] / (float)(kL * 3 - 1);
        float loss_imp = var / (mean * mean + 1e-10f);
        float loss_dyn = -ent_total / (float)(kBH * 3);
        out_loss[0] = loss_imp + 0.1f * loss_dyn;
    }
}

// ---------------------------------------------------------------------------
extern "C" void kernel_launch(void* const* d_in, const int* in_sizes, int n_in,
                              void* d_out, int out_size, void* d_ws, size_t ws_size,
                              hipStream_t stream) {
    const float* x     = (const float*)d_in[0];
    const float* masks = (const float*)d_in[1];
    const float* W1    = (const float*)d_in[2];
    const float* b1    = (const float*)d_in[3];
    const float* W2    = (const float*)d_in[4];
    const float* b2    = (const float*)d_in[5];
    const float* Wg    = (const float*)d_in[6];
    const float* Wp    = (const float*)d_in[7];
    const float* bp    = (const float*)d_in[8];
    float* out = (float*)d_out;
    float* ws  = (float*)d_ws;

    // workspace layout (floats)
    float* adj    = ws;                       // 16,777,216
    float* q      = adj + 16777216;           //  2,097,152
    float* k      = q + 2097152;              //  2,097,152
    float* xp     = k + 2097152;              //  2,097,152
    float* gbuf   = xp + 2097152;             //     98,304
    float* spbuf  = gbuf + 98304;             //     98,304
    float* entbuf = spbuf + 98304;            //     32,768

    k_qk<<<kB * kL, 256, 0, stream>>>(x, W1, b1, W2, b2, q, k);
    k_adj<<<kBH * 64, 256, 0, stream>>>(q, k, adj);
    k_select<<<kROWS / 4, 256, 0, stream>>>(adj, Wg, gbuf, spbuf, entbuf);
    k_xp<<<512, 256, 0, stream>>>(x, Wp, bp, xp);
    k_msoft<<<kROWS, 256, 0, stream>>>(adj, masks, gbuf);
    k_out<<<512, 256, 0, stream>>>(adj, xp, out);
    k_loss<<<1, 1024, 0, stream>>>(spbuf, entbuf, out + (size_t)kB * kL * kD);
}

// Round 2
// 282.832 us; speedup vs baseline: 1.7089x; 1.7089x over previous
//
#include <hip/hip_runtime.h>
#include <hip/hip_bf16.h>
#include <math.h>

// Problem constants
static constexpr int kB = 8;
static constexpr int kH = 8;
static constexpr int kL = 512;
static constexpr int kD = 512;
static constexpr int kDH = 64;     // D/H
static constexpr int kBH = 64;     // B*H
static constexpr int kROWS = kBH * kL;  // 32768

__device__ __forceinline__ float gelu_exact(float v) {
    return 0.5f * v * (1.0f + erff(v * 0.70710678118654752440f));
}

// ---------------------------------------------------------------------------
// K1: q = xh@W1^T + b1, k = xh@W2^T + b2 as tiled GEMM.
// grid = B*H*(L/64) = 512 blocks, 256 thr. Tile: 64(l) x 64(d), K=64.
// Thread (ty,tx): rows ty*4+a, cols tx+16*jj.
// ---------------------------------------------------------------------------
__global__ __launch_bounds__(256) void k_qk(const float* __restrict__ x,
        const float* __restrict__ W1, const float* __restrict__ b1,
        const float* __restrict__ W2, const float* __restrict__ b2,
        float* __restrict__ q, float* __restrict__ k) {
    int blk = blockIdx.x;              // b*64 + h*8 + lt
    int b = blk >> 6, h = (blk >> 3) & 7, lt = blk & 7;
    __shared__ float xt[64][68];       // [l][c]
    __shared__ float w1t[64][68];      // [d][c]
    __shared__ float w2t[64][68];
    int tid = threadIdx.x;
    #pragma unroll
    for (int r = 0; r < 16; ++r) {
        int e = tid + r * 256;
        int rr = e >> 6, cc = e & 63;
        xt[rr][cc]  = x[(b * kL + lt * 64 + rr) * kD + h * kDH + cc];
        w1t[rr][cc] = W1[rr * 64 + cc];
        w2t[rr][cc] = W2[rr * 64 + cc];
    }
    __syncthreads();
    int ty = tid >> 4, tx = tid & 15;
    float aq[4][4] = {}, ak[4][4] = {};
    #pragma unroll 2
    for (int c = 0; c < 64; c += 4) {
        float4 av[4], wq[4], wk[4];
        #pragma unroll
        for (int a = 0; a < 4; ++a) av[a] = *(const float4*)&xt[ty * 4 + a][c];
        #pragma unroll
        for (int j = 0; j < 4; ++j) {
            wq[j] = *(const float4*)&w1t[tx + 16 * j][c];
            wk[j] = *(const float4*)&w2t[tx + 16 * j][c];
        }
        #pragma unroll
        for (int a = 0; a < 4; ++a)
            #pragma unroll
            for (int j = 0; j < 4; ++j) {
                aq[a][j] = fmaf(av[a].x, wq[j].x, aq[a][j]);
                aq[a][j] = fmaf(av[a].y, wq[j].y, aq[a][j]);
                aq[a][j] = fmaf(av[a].z, wq[j].z, aq[a][j]);
                aq[a][j] = fmaf(av[a].w, wq[j].w, aq[a][j]);
                ak[a][j] = fmaf(av[a].x, wk[j].x, ak[a][j]);
                ak[a][j] = fmaf(av[a].y, wk[j].y, ak[a][j]);
                ak[a][j] = fmaf(av[a].z, wk[j].z, ak[a][j]);
                ak[a][j] = fmaf(av[a].w, wk[j].w, ak[a][j]);
            }
    }
    #pragma unroll
    for (int a = 0; a < 4; ++a)
        #pragma unroll
        for (int j = 0; j < 4; ++j) {
            int row = lt * 64 + ty * 4 + a;
            int col = tx + 16 * j;
            int o = ((b * kH + h) * kL + row) * kDH + col;
            q[o] = aq[a][j] + b1[col];
            k[o] = ak[a][j] + b2[col];
        }
}

// ---------------------------------------------------------------------------
// K2: adj = gelu(q @ k^T) per (b,h).  64x64 tile per block, K=64.
// grid = B*H*8*8 = 4096.  A=q natural [i][c], B=k natural [j][c].
// ---------------------------------------------------------------------------
__global__ __launch_bounds__(256) void k_adj(const float* __restrict__ q,
        const float* __restrict__ k, float* __restrict__ adj) {
    int blk = blockIdx.x;
    int bh = blk >> 6;
    int it = (blk >> 3) & 7, jt = blk & 7;
    __shared__ float qs[64][68];
    __shared__ float ks[64][68];
    int tid = threadIdx.x;
    const float* qb = q + (bh * kL + it * 64) * kDH;
    const float* kb = k + (bh * kL + jt * 64) * kDH;
    #pragma unroll
    for (int r = 0; r < 16; ++r) {
        int e = tid + r * 256;
        int rr = e >> 6, cc = e & 63;
        qs[rr][cc] = qb[rr * 64 + cc];
        ks[rr][cc] = kb[rr * 64 + cc];
    }
    __syncthreads();
    int ty = tid >> 4, tx = tid & 15;
    float acc[4][4] = {};
    #pragma unroll 2
    for (int c = 0; c < 64; c += 4) {
        float4 av[4], bv[4];
        #pragma unroll
        for (int a = 0; a < 4; ++a) av[a] = *(const float4*)&qs[ty * 4 + a][c];
        #pragma unroll
        for (int j = 0; j < 4; ++j) bv[j] = *(const float4*)&ks[tx + 16 * j][c];
        #pragma unroll
        for (int a = 0; a < 4; ++a)
            #pragma unroll
            for (int j = 0; j < 4; ++j) {
                acc[a][j] = fmaf(av[a].x, bv[j].x, acc[a][j]);
                acc[a][j] = fmaf(av[a].y, bv[j].y, acc[a][j]);
                acc[a][j] = fmaf(av[a].z, bv[j].z, acc[a][j]);
                acc[a][j] = fmaf(av[a].w, bv[j].w, acc[a][j]);
            }
    }
    #pragma unroll
    for (int a = 0; a < 4; ++a)
        #pragma unroll
        for (int j = 0; j < 4; ++j) {
            int row = it * 64 + ty * 4 + a;
            int col = jt * 64 + tx + 16 * j;
            adj[((size_t)bh * kL + row) * kL + col] = gelu_exact(acc[a][j]);
        }
}

// ---------------------------------------------------------------------------
// K3: per-row (one wave): exact 256th-smallest via bitwise radix select,
// threshold, write back, logits = row @ Wg^T, softmax-3, stable top-p,
// gates/sp/entropy out.   grid = ROWS/4 blocks of 256 (4 waves)
// ---------------------------------------------------------------------------
__global__ __launch_bounds__(256) void k_select(float* __restrict__ adj,
        const float* __restrict__ Wg, float* __restrict__ gbuf,
        float* __restrict__ spbuf, float* __restrict__ entbuf) {
    int tid = threadIdx.x;
    int wave = tid >> 6, lane = tid & 63;
    int row = blockIdx.x * 4 + wave;
    float* arow = adj + (size_t)row * kL;

    float v[8];
    unsigned key[8];
    #pragma unroll
    for (int t = 0; t < 8; ++t) {
        v[t] = arow[t * 64 + lane];
        unsigned u = __float_as_uint(v[t]);
        key[t] = (u & 0x80000000u) ? ~u : (u | 0x80000000u);
    }
    // exact k-th smallest (k = 255, 0-indexed) via MSB-first bit select
    unsigned prefix = 0;
    unsigned act = 0xFFu;
    int kk = 255;
    for (int bit = 31; bit >= 0; --bit) {
        int c = 0;
        #pragma unroll
        for (int t = 0; t < 8; ++t)
            if (((act >> t) & 1u) && !((key[t] >> bit) & 1u)) ++c;
        #pragma unroll
        for (int off = 1; off < 64; off <<= 1) c += __shfl_xor(c, off);
        if (kk < c) {
            #pragma unroll
            for (int t = 0; t < 8; ++t)
                if ((key[t] >> bit) & 1u) act &= ~(1u << t);
        } else {
            kk -= c;
            prefix |= (1u << bit);
            #pragma unroll
            for (int t = 0; t < 8; ++t)
                if (!((key[t] >> bit) & 1u)) act &= ~(1u << t);
        }
    }
    float thr = (prefix & 0x80000000u) ? __uint_as_float(prefix ^ 0x80000000u)
                                       : __uint_as_float(~prefix);
    // threshold + logits
    float l0 = 0.f, l1 = 0.f, l2 = 0.f;
    #pragma unroll
    for (int t = 0; t < 8; ++t) {
        float nv = (v[t] > thr) ? v[t] : 0.0f;
        arow[t * 64 + lane] = nv;
        int j = t * 64 + lane;
        l0 = fmaf(nv, Wg[j], l0);
        l1 = fmaf(nv, Wg[kL + j], l1);
        l2 = fmaf(nv, Wg[2 * kL + j], l2);
    }
    #pragma unroll
    for (int off = 1; off < 64; off <<= 1) {
        l0 += __shfl_xor(l0, off);
        l1 += __shfl_xor(l1, off);
        l2 += __shfl_xor(l2, off);
    }
    if (lane == 0) {
        float m = fmaxf(l0, fmaxf(l1, l2));
        float e0 = expf(l0 - m), e1 = expf(l1 - m), e2 = expf(l2 - m);
        float s = e0 + e1 + e2;
        float p[3] = {e0 / s, e1 / s, e2 / s};
        // stable argsort of -p (descending p, ties -> lower index)
        int o0, o1, o2;
        if (p[0] >= p[1] && p[0] >= p[2]) o0 = 0;
        else if (p[1] >= p[2]) o0 = 1;
        else o0 = 2;
        int r0 = (o0 == 0) ? 1 : 0;
        int r1 = (o0 == 2) ? 1 : 2;
        if (p[r0] >= p[r1]) { o1 = r0; o2 = r1; } else { o1 = r1; o2 = r0; }
        float sp0 = p[o0], sp1 = p[o1], sp2 = p[o2];
        float c0 = sp0, c1 = sp0 + sp1, c2 = c1 + sp2;
        bool m0 = c0 > 0.5f, m1 = c1 > 0.5f, m2 = c2 > 0.5f;
        int ti = m0 ? 0 : (m1 ? 1 : 2);
        bool mm0 = m0 && (ti != 0);
        bool mm1 = m1 && (ti != 1);
        bool mm2 = m2 && (ti != 2);
        float g[3] = {0.f, 0.f, 0.f};
        g[o0] = mm0 ? 0.f : 1.f;
        g[o1] = mm1 ? 0.f : 1.f;
        g[o2] = mm2 ? 0.f : 1.f;
        gbuf[row * 3 + 0] = g[0];
        gbuf[row * 3 + 1] = g[1];
        gbuf[row * 3 + 2] = g[2];
        spbuf[row * 3 + 0] = mm0 ? 0.f : sp0;
        spbuf[row * 3 + 1] = mm1 ? 0.f : sp1;
        spbuf[row * 3 + 2] = mm2 ? 0.f : sp2;
        entbuf[row] = p[0] * logf(p[0] + 1e-10f) +
                      p[1] * logf(p[1] + 1e-10f) +
                      p[2] * logf(p[2] + 1e-10f);
    }
}

// ---------------------------------------------------------------------------
// K4: xp = x @ Wp^T + bp.  (B*L, 512) x (512, 512)^T. grid = 64*8 = 512
// ---------------------------------------------------------------------------
__global__ __launch_bounds__(256) void k_xp(const float* __restrict__ x,
        const float* __restrict__ Wp, const float* __restrict__ bp,
        float* __restrict__ xp) {
    int it = blockIdx.x >> 3, jt = blockIdx.x & 7;
    __shared__ float xs[64][68];
    __shared__ float ws[64][68];
    int tid = threadIdx.x;
    int ty = tid >> 4, tx = tid & 15;
    float acc[4][4] = {};
    for (int kb = 0; kb < 8; ++kb) {
        #pragma unroll
        for (int r = 0; r < 16; ++r) {
            int e = tid + r * 256;
            int rr = e >> 6, cc = e & 63;
            xs[rr][cc] = x[(it * 64 + rr) * kD + kb * 64 + cc];
            ws[rr][cc] = Wp[(jt * 64 + rr) * kD + kb * 64 + cc];
        }
        __syncthreads();
        #pragma unroll 2
        for (int c = 0; c < 64; c += 4) {
            float4 av[4], bv[4];
            #pragma unroll
            for (int a = 0; a < 4; ++a) av[a] = *(const float4*)&xs[ty * 4 + a][c];
            #pragma unroll
            for (int j = 0; j < 4; ++j) bv[j] = *(const float4*)&ws[tx + 16 * j][c];
            #pragma unroll
            for (int a = 0; a < 4; ++a)
                #pragma unroll
                for (int j = 0; j < 4; ++j) {
                    acc[a][j] = fmaf(av[a].x, bv[j].x, acc[a][j]);
                    acc[a][j] = fmaf(av[a].y, bv[j].y, acc[a][j]);
                    acc[a][j] = fmaf(av[a].z, bv[j].z, acc[a][j]);
                    acc[a][j] = fmaf(av[a].w, bv[j].w, acc[a][j]);
                }
        }
        __syncthreads();
    }
    #pragma unroll
    for (int a = 0; a < 4; ++a)
        #pragma unroll
        for (int j = 0; j < 4; ++j) {
            int col = jt * 64 + tx + 16 * j;
            xp[(it * 64 + ty * 4 + a) * kD + col] = acc[a][j] + bp[col];
        }
}

// ---------------------------------------------------------------------------
// K5: per-row mask build + masked softmax + L1 renorm, in place.
// One wave per row; grid = ROWS/4 blocks of 256.
// ---------------------------------------------------------------------------
__global__ __launch_bounds__(256) void k_msoft(float* __restrict__ adj,
        const float* __restrict__ masks, const float* __restrict__ gbuf) {
    int tid = threadIdx.x;
    int wv = tid >> 6, lane = tid & 63;
    int row = blockIdx.x * 4 + wv;
    int i = row & (kL - 1);
    float g0 = gbuf[row * 3 + 0];
    float g1 = gbuf[row * 3 + 1];
    float g2 = gbuf[row * 3 + 2];
    const float* m0 = masks + (i * 3 + 0) * kL;
    const float* m1 = masks + (i * 3 + 1) * kL;
    const float* m2 = masks + (i * 3 + 2) * kL;
    float* arow = adj + (size_t)row * kL;
    int j0 = lane * 8;

    float av[8];
    #pragma unroll
    for (int half = 0; half < 2; ++half) {
        float4 a4 = *(const float4*)&arow[j0 + half * 4];
        float4 v0 = *(const float4*)&m0[j0 + half * 4];
        float4 v1 = *(const float4*)&m1[j0 + half * 4];
        float4 v2 = *(const float4*)&m2[j0 + half * 4];
        float mv[4];
        mv[0] = g0 * v0.x + g1 * v1.x + g2 * v2.x;
        mv[1] = g0 * v0.y + g1 * v1.y + g2 * v2.y;
        mv[2] = g0 * v0.z + g1 * v1.z + g2 * v2.z;
        mv[3] = g0 * v0.w + g1 * v1.w + g2 * v2.w;
        float a[4] = {a4.x, a4.y, a4.z, a4.w};
        #pragma unroll
        for (int t = 0; t < 4; ++t) {
            int j = j0 + half * 4 + t;
            float mm = mv[t] + ((j == i) ? 1.0f : 0.0f);
            av[half * 4 + t] = a[t] * mm;
        }
    }
    // wave max
    float mx = av[0];
    #pragma unroll
    for (int t = 1; t < 8; ++t) mx = fmaxf(mx, av[t]);
    #pragma unroll
    for (int off = 1; off < 64; off <<= 1) mx = fmaxf(mx, __shfl_xor(mx, off));
    float e[8], ls = 0.f;
    #pragma unroll
    for (int t = 0; t < 8; ++t) { e[t] = expf(av[t] - mx); ls += e[t]; }
    #pragma unroll
    for (int off = 1; off < 64; off <<= 1) ls += __shfl_xor(ls, off);
    float inv = 1.0f / ls;
    float p[8], l1s = 0.f;
    #pragma unroll
    for (int t = 0; t < 8; ++t) { p[t] = e[t] * inv; l1s += fabsf(p[t]); }
    #pragma unroll
    for (int off = 1; off < 64; off <<= 1) l1s += __shfl_xor(l1s, off);
    float s2 = 1.0f / fmaxf(l1s, 1e-12f);
    float4 o0 = make_float4(p[0] * s2, p[1] * s2, p[2] * s2, p[3] * s2);
    float4 o1 = make_float4(p[4] * s2, p[5] * s2, p[6] * s2, p[7] * s2);
    *(float4*)&arow[j0]     = o0;
    *(float4*)&arow[j0 + 4] = o1;
}

// ---------------------------------------------------------------------------
// K6: out[b,i,h,d] = sum_j adjn[bh,i,j] * xp[b,j,h*64+d].
// grid = B*H*8 = 512 blocks; 64x64 tile, K=512 in chunks of 64.
// A = adj natural [i][j]; B = xp natural [j][d]; B-frag read along d.
// Thread (ty,tx): rows ty*4+a, cols tx*4..tx*4+3 (float4 stores).
// ---------------------------------------------------------------------------
__global__ __launch_bounds__(256) void k_out(const float* __restrict__ adj,
        const float* __restrict__ xp, float* __restrict__ out) {
    int blk = blockIdx.x;
    int bh = blk >> 3;
    int it = blk & 7;
    int b = bh >> 3, h = bh & 7;
    __shared__ float as_[64][68];
    __shared__ float xs[64][68];
    int tid = threadIdx.x;
    int ty = tid >> 4, tx = tid & 15;
    float acc[4][4] = {};
    for (int kb = 0; kb < 8; ++kb) {
        #pragma unroll
        for (int r = 0; r < 16; ++r) {
            int e = tid + r * 256;
            int rr = e >> 6, cc = e & 63;
            as_[rr][cc] = adj[((size_t)bh * kL + it * 64 + rr) * kL + kb * 64 + cc];
            xs[rr][cc] = xp[((size_t)b * kL + kb * 64 + rr) * kD + h * 64 + cc];
        }
        __syncthreads();
        #pragma unroll 2
        for (int j = 0; j < 64; j += 4) {
            float4 av[4];
            #pragma unroll
            for (int a = 0; a < 4; ++a) av[a] = *(const float4*)&as_[ty * 4 + a][j];
            float4 bv[4];
            #pragma unroll
            for (int jj = 0; jj < 4; ++jj) bv[jj] = *(const float4*)&xs[j + jj][tx * 4];
            #pragma unroll
            for (int a = 0; a < 4; ++a) {
                acc[a][0] = fmaf(av[a].x, bv[0].x, acc[a][0]);
                acc[a][1] = fmaf(av[a].x, bv[0].y, acc[a][1]);
                acc[a][2] = fmaf(av[a].x, bv[0].z, acc[a][2]);
                acc[a][3] = fmaf(av[a].x, bv[0].w, acc[a][3]);
                acc[a][0] = fmaf(av[a].y, bv[1].x, acc[a][0]);
                acc[a][1] = fmaf(av[a].y, bv[1].y, acc[a][1]);
                acc[a][2] = fmaf(av[a].y, bv[1].z, acc[a][2]);
                acc[a][3] = fmaf(av[a].y, bv[1].w, acc[a][3]);
                acc[a][0] = fmaf(av[a].z, bv[2].x, acc[a][0]);
                acc[a][1] = fmaf(av[a].z, bv[2].y, acc[a][1]);
                acc[a][2] = fmaf(av[a].z, bv[2].z, acc[a][2]);
                acc[a][3] = fmaf(av[a].z, bv[2].w, acc[a][3]);
                acc[a][0] = fmaf(av[a].w, bv[3].x, acc[a][0]);
                acc[a][1] = fmaf(av[a].w, bv[3].y, acc[a][1]);
                acc[a][2] = fmaf(av[a].w, bv[3].z, acc[a][2]);
                acc[a][3] = fmaf(av[a].w, bv[3].w, acc[a][3]);
            }
        }
        __syncthreads();
    }
    #pragma unroll
    for (int a = 0; a < 4; ++a) {
        float4 o = make_float4(acc[a][0], acc[a][1], acc[a][2], acc[a][3]);
        *(float4*)&out[((size_t)b * kL + it * 64 + ty * 4 + a) * kD + h * 64 + tx * 4] = o;
    }
}

// ---------------------------------------------------------------------------
// K7: finalize loss (single block, deterministic reductions)
// ---------------------------------------------------------------------------
__global__ __launch_bounds__(1024) void k_loss(const float* __restrict__ spbuf,
        const float* __restrict__ entbuf, float* __restrict__ out_loss) {
    __shared__ float imps[kL * 3];
    __shared__ float red[1024];
    int tid = threadIdx.x;
    for (int idx = tid; idx < kL * 3; idx += 1024) {
        float s = 0.f;
        for (int bh = 0; bh < kBH; ++bh)
            s += spbuf[bh * kL * 3 + idx];
        imps[idx] = s;
    }
    float es = 0.f;
    for (int idx = tid; idx < kROWS; idx += 1024) es += entbuf[idx];
    red[tid] = es;
    __syncthreads();
    for (int s = 512; s > 0; s >>= 1) {
        if (tid < s) red[tid] += red[tid + s];
        __syncthreads();
    }
    float ent_total = red[0];
    __syncthreads();
    float ms = 0.f;
    for (int idx = tid; idx < kL * 3; idx += 1024) ms += imps[idx];
    red[tid] = ms;
    __syncthreads();
    for (int s = 512; s > 0; s >>= 1) {
        if (tid < s) red[tid] += red[tid + s];
        __syncthreads();
    }
    float mean = red[0] / (float)(kL * 3);
    __syncthreads();
    float vs = 0.f;
    for (int idx = tid; idx < kL * 3; idx += 1024) {
        float d = imps[idx] - mean;
        vs += d * d;
    }
    red[tid] = vs;
    __syncthreads();
    for (int s = 512; s > 0; s >>= 1) {
        if (tid < s) red[tid] += red[tid + s];
        __syncthreads();
    }
    if (tid == 0) {
        float var = red[0] / (float)(kL * 3 - 1);
        float loss_imp = var / (mean * mean + 1e-10f);
        float loss_dyn = -ent_total / (float)(kBH * 3);
        out_loss[0] = loss_imp + 0.1f * loss_dyn;
    }
}

// ---------------------------------------------------------------------------
extern "C" void kernel_launch(void* const* d_in, const int* in_sizes, int n_in,
                              void* d_out, int out_size, void* d_ws, size_t ws_size,
                              hipStream_t stream) {
    const float* x     = (const float*)d_in[0];
    const float* masks = (const float*)d_in[1];
    const float* W1    = (const float*)d_in[2];
    const float* b1    = (const float*)d_in[3];
    const float* W2    = (const float*)d_in[4];
    const float* b2    = (const float*)d_in[5];
    const float* Wg    = (const float*)d_in[6];
    const float* Wp    = (const float*)d_in[7];
    const float* bp    = (const float*)d_in[8];
    float* out = (float*)d_out;
    float* ws  = (float*)d_ws;

    float* adj    = ws;                       // 16,777,216
    float* q      = adj + 16777216;           //  2,097,152
    float* k      = q + 2097152;              //  2,097,152
    float* xp     = k + 2097152;              //  2,097,152
    float* gbuf   = xp + 2097152;             //     98,304
    float* spbuf  = gbuf + 98304;             //     98,304
    float* entbuf = spbuf + 98304;            //     32,768

    k_qk<<<512, 256, 0, stream>>>(x, W1, b1, W2, b2, q, k);
    k_adj<<<kBH * 64, 256, 0, stream>>>(q, k, adj);
    k_select<<<kROWS / 4, 256, 0, stream>>>(adj, Wg, gbuf, spbuf, entbuf);
    k_xp<<<512, 256, 0, stream>>>(x, Wp, bp, xp);
    k_msoft<<<kROWS / 4, 256, 0, stream>>>(adj, masks, gbuf);
    k_out<<<512, 256, 0, stream>>>(adj, xp, out);
    k_loss<<<1, 1024, 0, stream>>>(spbuf, entbuf, out + (size_t)kB * kL * kD);
}

// Round 3
// 217.319 us; speedup vs baseline: 2.2240x; 1.3015x over previous
//
#include <hip/hip_runtime.h>
#include <hip/hip_bf16.h>
#include <math.h>

// Problem constants
static constexpr int kB = 8;
static constexpr int kH = 8;
static constexpr int kL = 512;
static constexpr int kD = 512;
static constexpr int kDH = 64;     // D/H
static constexpr int kBH = 64;     // B*H
static constexpr int kROWS = kBH * kL;  // 32768

__device__ __forceinline__ float gelu_exact(float v) {
    return 0.5f * v * (1.0f + erff(v * 0.70710678118654752440f));
}

// ---------------------------------------------------------------------------
// K1: q = xh@W1^T + b1, k = xh@W2^T + b2 as tiled GEMM.
// ---------------------------------------------------------------------------
__global__ __launch_bounds__(256) void k_qk(const float* __restrict__ x,
        const float* __restrict__ W1, const float* __restrict__ b1,
        const float* __restrict__ W2, const float* __restrict__ b2,
        float* __restrict__ q, float* __restrict__ k) {
    int blk = blockIdx.x;              // b*64 + h*8 + lt
    int b = blk >> 6, h = (blk >> 3) & 7, lt = blk & 7;
    __shared__ float xt[64][68];       // [l][c]
    __shared__ float w1t[64][68];      // [d][c]
    __shared__ float w2t[64][68];
    int tid = threadIdx.x;
    #pragma unroll
    for (int r = 0; r < 16; ++r) {
        int e = tid + r * 256;
        int rr = e >> 6, cc = e & 63;
        xt[rr][cc]  = x[(b * kL + lt * 64 + rr) * kD + h * kDH + cc];
        w1t[rr][cc] = W1[rr * 64 + cc];
        w2t[rr][cc] = W2[rr * 64 + cc];
    }
    __syncthreads();
    int ty = tid >> 4, tx = tid & 15;
    float aq[4][4] = {}, ak[4][4] = {};
    #pragma unroll 2
    for (int c = 0; c < 64; c += 4) {
        float4 av[4], wq[4], wk[4];
        #pragma unroll
        for (int a = 0; a < 4; ++a) av[a] = *(const float4*)&xt[ty * 4 + a][c];
        #pragma unroll
        for (int j = 0; j < 4; ++j) {
            wq[j] = *(const float4*)&w1t[tx + 16 * j][c];
            wk[j] = *(const float4*)&w2t[tx + 16 * j][c];
        }
        #pragma unroll
        for (int a = 0; a < 4; ++a)
            #pragma unroll
            for (int j = 0; j < 4; ++j) {
                aq[a][j] = fmaf(av[a].x, wq[j].x, aq[a][j]);
                aq[a][j] = fmaf(av[a].y, wq[j].y, aq[a][j]);
                aq[a][j] = fmaf(av[a].z, wq[j].z, aq[a][j]);
                aq[a][j] = fmaf(av[a].w, wq[j].w, aq[a][j]);
                ak[a][j] = fmaf(av[a].x, wk[j].x, ak[a][j]);
                ak[a][j] = fmaf(av[a].y, wk[j].y, ak[a][j]);
                ak[a][j] = fmaf(av[a].z, wk[j].z, ak[a][j]);
                ak[a][j] = fmaf(av[a].w, wk[j].w, ak[a][j]);
            }
    }
    #pragma unroll
    for (int a = 0; a < 4; ++a)
        #pragma unroll
        for (int j = 0; j < 4; ++j) {
            int row = lt * 64 + ty * 4 + a;
            int col = tx + 16 * j;
            int o = ((b * kH + h) * kL + row) * kDH + col;
            q[o] = aq[a][j] + b1[col];
            k[o] = ak[a][j] + b2[col];
        }
}

// ---------------------------------------------------------------------------
// K2: adj = gelu(q @ k^T) per (b,h).  64x64 tile per block, K=64.
// ---------------------------------------------------------------------------
__global__ __launch_bounds__(256) void k_adj(const float* __restrict__ q,
        const float* __restrict__ k, float* __restrict__ adj) {
    int blk = blockIdx.x;
    int bh = blk >> 6;
    int it = (blk >> 3) & 7, jt = blk & 7;
    __shared__ float qs[64][68];
    __shared__ float ks[64][68];
    int tid = threadIdx.x;
    const float* qb = q + (bh * kL + it * 64) * kDH;
    const float* kb = k + (bh * kL + jt * 64) * kDH;
    #pragma unroll
    for (int r = 0; r < 16; ++r) {
        int e = tid + r * 256;
        int rr = e >> 6, cc = e & 63;
        qs[rr][cc] = qb[rr * 64 + cc];
        ks[rr][cc] = kb[rr * 64 + cc];
    }
    __syncthreads();
    int ty = tid >> 4, tx = tid & 15;
    float acc[4][4] = {};
    #pragma unroll 2
    for (int c = 0; c < 64; c += 4) {
        float4 av[4], bv[4];
        #pragma unroll
        for (int a = 0; a < 4; ++a) av[a] = *(const float4*)&qs[ty * 4 + a][c];
        #pragma unroll
        for (int j = 0; j < 4; ++j) bv[j] = *(const float4*)&ks[tx + 16 * j][c];
        #pragma unroll
        for (int a = 0; a < 4; ++a)
            #pragma unroll
            for (int j = 0; j < 4; ++j) {
                acc[a][j] = fmaf(av[a].x, bv[j].x, acc[a][j]);
                acc[a][j] = fmaf(av[a].y, bv[j].y, acc[a][j]);
                acc[a][j] = fmaf(av[a].z, bv[j].z, acc[a][j]);
                acc[a][j] = fmaf(av[a].w, bv[j].w, acc[a][j]);
            }
    }
    #pragma unroll
    for (int a = 0; a < 4; ++a)
        #pragma unroll
        for (int j = 0; j < 4; ++j) {
            int row = it * 64 + ty * 4 + a;
            int col = jt * 64 + tx + 16 * j;
            adj[((size_t)bh * kL + row) * kL + col] = gelu_exact(acc[a][j]);
        }
}

// ---------------------------------------------------------------------------
// K3 (fused): per-row, one wave:
//  - exact 256th-smallest via monotone bisection w/ early exit (bit-exact)
//  - threshold
//  - logits = row @ Wg^T, softmax-3, stable top-p -> gates (+sp/ent for loss)
//  - mask build + diag, masked row softmax, L1 renorm, single adj write
// grid = ROWS/4 blocks of 256 (4 waves/block). Lane owns j = lane*8..+7.
// ---------------------------------------------------------------------------
__global__ __launch_bounds__(256) void k_select(float* __restrict__ adj,
        const float* __restrict__ Wg, const float* __restrict__ masks,
        float* __restrict__ spbuf, float* __restrict__ entbuf) {
    int tid = threadIdx.x;
    int wave = tid >> 6, lane = tid & 63;
    int row = blockIdx.x * 4 + wave;
    int i = row & (kL - 1);
    float* arow = adj + (size_t)row * kL;
    int j0 = lane * 8;

    // load 8 contiguous elements (vectorized), build monotone keys
    float v[8];
    {
        float4 a0 = *(const float4*)&arow[j0];
        float4 a1 = *(const float4*)&arow[j0 + 4];
        v[0] = a0.x; v[1] = a0.y; v[2] = a0.z; v[3] = a0.w;
        v[4] = a1.x; v[5] = a1.y; v[6] = a1.z; v[7] = a1.w;
    }
    unsigned key[8];
    #pragma unroll
    for (int t = 0; t < 8; ++t) {
        unsigned u = __float_as_uint(v[t]);
        key[t] = (u & 0x80000000u) ? ~u : (u | 0x80000000u);
    }

    // exact k-th smallest (k=255 0-indexed) by bisection on key space.
    // invariant: kth key in [prefix, prefix + 2^(bit+1)), cbp = #{key<prefix},
    // cin = #keys in the interval. Early-exit when cin==1.
    unsigned prefix = 0;
    int cbp = 0, cin = 512;
    int bit = 31;
    while (cin > 1 && bit >= 0) {
        unsigned cand = prefix | (1u << bit);
        int c = 0;
        #pragma unroll
        for (int t = 0; t < 8; ++t) c += (key[t] < cand) ? 1 : 0;
        #pragma unroll
        for (int off = 1; off < 64; off <<= 1) c += __shfl_xor(c, off);
        if (255 < c) {
            cin = c - cbp;               // kth in [prefix, cand)
        } else {
            cin -= (c - cbp);            // kth in [cand, hi)
            prefix = cand;
            cbp = c;
        }
        --bit;
    }
    // extract the kth key: unique key (or duplicated prefix) in
    // [prefix, prefix + width), width = 1<<(bit+1)  (bit in [-1,30])
    unsigned width = 1u << (bit + 1);
    unsigned kk2 = 0;
    #pragma unroll
    for (int t = 0; t < 8; ++t) {
        unsigned d = key[t] - prefix;    // unsigned wrap makes d<width an interval test
        if (d < width) kk2 = max(kk2, key[t]);
    }
    #pragma unroll
    for (int off = 1; off < 64; off <<= 1) kk2 = max(kk2, (unsigned)__shfl_xor((int)kk2, off));
    float thr = (kk2 & 0x80000000u) ? __uint_as_float(kk2 & 0x7fffffffu)
                                    : __uint_as_float(~kk2);

    // threshold + logits (j = j0 + t mapping)
    float l0 = 0.f, l1 = 0.f, l2 = 0.f;
    #pragma unroll
    for (int t = 0; t < 8; ++t) {
        float nv = (v[t] > thr) ? v[t] : 0.0f;
        v[t] = nv;
        int j = j0 + t;
        l0 = fmaf(nv, Wg[j], l0);
        l1 = fmaf(nv, Wg[kL + j], l1);
        l2 = fmaf(nv, Wg[2 * kL + j], l2);
    }
    #pragma unroll
    for (int off = 1; off < 64; off <<= 1) {
        l0 += __shfl_xor(l0, off);
        l1 += __shfl_xor(l1, off);
        l2 += __shfl_xor(l2, off);
    }
    // softmax-3 + stable top-p (all lanes redundantly; values wave-uniform)
    float m = fmaxf(l0, fmaxf(l1, l2));
    float e0 = expf(l0 - m), e1 = expf(l1 - m), e2 = expf(l2 - m);
    float s = e0 + e1 + e2;
    float p[3] = {e0 / s, e1 / s, e2 / s};
    int o0, o1, o2;
    if (p[0] >= p[1] && p[0] >= p[2]) o0 = 0;
    else if (p[1] >= p[2]) o0 = 1;
    else o0 = 2;
    int r0 = (o0 == 0) ? 1 : 0;
    int r1 = (o0 == 2) ? 1 : 2;
    if (p[r0] >= p[r1]) { o1 = r0; o2 = r1; } else { o1 = r1; o2 = r0; }
    float sp0 = p[o0], sp1 = p[o1], sp2 = p[o2];
    float c0 = sp0, c1 = sp0 + sp1, c2 = c1 + sp2;
    bool m0 = c0 > 0.5f, m1 = c1 > 0.5f, m2 = c2 > 0.5f;
    int ti = m0 ? 0 : (m1 ? 1 : 2);
    bool mm0 = m0 && (ti != 0);
    bool mm1 = m1 && (ti != 1);
    bool mm2 = m2 && (ti != 2);
    float g[3] = {0.f, 0.f, 0.f};
    g[o0] = mm0 ? 0.f : 1.f;
    g[o1] = mm1 ? 0.f : 1.f;
    g[o2] = mm2 ? 0.f : 1.f;
    if (lane == 0) {
        spbuf[row * 3 + 0] = mm0 ? 0.f : sp0;
        spbuf[row * 3 + 1] = mm1 ? 0.f : sp1;
        spbuf[row * 3 + 2] = mm2 ? 0.f : sp2;
        entbuf[row] = p[0] * logf(p[0] + 1e-10f) +
                      p[1] * logf(p[1] + 1e-10f) +
                      p[2] * logf(p[2] + 1e-10f);
    }

    // mask build + diag, apply to thresholded values
    const float* mk0 = masks + (i * 3 + 0) * kL + j0;
    const float* mk1 = masks + (i * 3 + 1) * kL + j0;
    const float* mk2 = masks + (i * 3 + 2) * kL + j0;
    float av[8];
    #pragma unroll
    for (int half = 0; half < 2; ++half) {
        float4 v0 = *(const float4*)&mk0[half * 4];
        float4 v1 = *(const float4*)&mk1[half * 4];
        float4 v2 = *(const float4*)&mk2[half * 4];
        float mv[4];
        mv[0] = g[0] * v0.x + g[1] * v1.x + g[2] * v2.x;
        mv[1] = g[0] * v0.y + g[1] * v1.y + g[2] * v2.y;
        mv[2] = g[0] * v0.z + g[1] * v1.z + g[2] * v2.z;
        mv[3] = g[0] * v0.w + g[1] * v1.w + g[2] * v2.w;
        #pragma unroll
        for (int t = 0; t < 4; ++t) {
            int j = j0 + half * 4 + t;
            float mm = mv[t] + ((j == i) ? 1.0f : 0.0f);
            av[half * 4 + t] = v[half * 4 + t] * mm;
        }
    }
    // masked row softmax + L1 renorm
    float mx = av[0];
    #pragma unroll
    for (int t = 1; t < 8; ++t) mx = fmaxf(mx, av[t]);
    #pragma unroll
    for (int off = 1; off < 64; off <<= 1) mx = fmaxf(mx, __shfl_xor(mx, off));
    float e[8], ls = 0.f;
    #pragma unroll
    for (int t = 0; t < 8; ++t) { e[t] = expf(av[t] - mx); ls += e[t]; }
    #pragma unroll
    for (int off = 1; off < 64; off <<= 1) ls += __shfl_xor(ls, off);
    float inv = 1.0f / ls;
    float pp[8], l1s = 0.f;
    #pragma unroll
    for (int t = 0; t < 8; ++t) { pp[t] = e[t] * inv; l1s += fabsf(pp[t]); }
    #pragma unroll
    for (int off = 1; off < 64; off <<= 1) l1s += __shfl_xor(l1s, off);
    float s2 = 1.0f / fmaxf(l1s, 1e-12f);
    float4 w0 = make_float4(pp[0] * s2, pp[1] * s2, pp[2] * s2, pp[3] * s2);
    float4 w1 = make_float4(pp[4] * s2, pp[5] * s2, pp[6] * s2, pp[7] * s2);
    *(float4*)&arow[j0]     = w0;
    *(float4*)&arow[j0 + 4] = w1;
}

// ---------------------------------------------------------------------------
// K4: xp = x @ Wp^T + bp.  (B*L, 512) x (512, 512)^T. grid = 64*8 = 512
// ---------------------------------------------------------------------------
__global__ __launch_bounds__(256) void k_xp(const float* __restrict__ x,
        const float* __restrict__ Wp, const float* __restrict__ bp,
        float* __restrict__ xp) {
    int it = blockIdx.x >> 3, jt = blockIdx.x & 7;
    __shared__ float xs[64][68];
    __shared__ float ws[64][68];
    int tid = threadIdx.x;
    int ty = tid >> 4, tx = tid & 15;
    float acc[4][4] = {};
    for (int kb = 0; kb < 8; ++kb) {
        #pragma unroll
        for (int r = 0; r < 16; ++r) {
            int e = tid + r * 256;
            int rr = e >> 6, cc = e & 63;
            xs[rr][cc] = x[(it * 64 + rr) * kD + kb * 64 + cc];
            ws[rr][cc] = Wp[(jt * 64 + rr) * kD + kb * 64 + cc];
        }
        __syncthreads();
        #pragma unroll 2
        for (int c = 0; c < 64; c += 4) {
            float4 av[4], bv[4];
            #pragma unroll
            for (int a = 0; a < 4; ++a) av[a] = *(const float4*)&xs[ty * 4 + a][c];
            #pragma unroll
            for (int j = 0; j < 4; ++j) bv[j] = *(const float4*)&ws[tx + 16 * j][c];
            #pragma unroll
            for (int a = 0; a < 4; ++a)
                #pragma unroll
                for (int j = 0; j < 4; ++j) {
                    acc[a][j] = fmaf(av[a].x, bv[j].x, acc[a][j]);
                    acc[a][j] = fmaf(av[a].y, bv[j].y, acc[a][j]);
                    acc[a][j] = fmaf(av[a].z, bv[j].z, acc[a][j]);
                    acc[a][j] = fmaf(av[a].w, bv[j].w, acc[a][j]);
                }
        }
        __syncthreads();
    }
    #pragma unroll
    for (int a = 0; a < 4; ++a)
        #pragma unroll
        for (int j = 0; j < 4; ++j) {
            int col = jt * 64 + tx + 16 * j;
            xp[(it * 64 + ty * 4 + a) * kD + col] = acc[a][j] + bp[col];
        }
}

// ---------------------------------------------------------------------------
// K6: out[b,i,h,d] = sum_j adjn[bh,i,j] * xp[b,j,h*64+d].
// ---------------------------------------------------------------------------
__global__ __launch_bounds__(256) void k_out(const float* __restrict__ adj,
        const float* __restrict__ xp, float* __restrict__ out) {
    int blk = blockIdx.x;
    int bh = blk >> 3;
    int it = blk & 7;
    int b = bh >> 3, h = bh & 7;
    __shared__ float as_[64][68];
    __shared__ float xs[64][68];
    int tid = threadIdx.x;
    int ty = tid >> 4, tx = tid & 15;
    float acc[4][4] = {};
    for (int kb = 0; kb < 8; ++kb) {
        #pragma unroll
        for (int r = 0; r < 16; ++r) {
            int e = tid + r * 256;
            int rr = e >> 6, cc = e & 63;
            as_[rr][cc] = adj[((size_t)bh * kL + it * 64 + rr) * kL + kb * 64 + cc];
            xs[rr][cc] = xp[((size_t)b * kL + kb * 64 + rr) * kD + h * 64 + cc];
        }
        __syncthreads();
        #pragma unroll 2
        for (int j = 0; j < 64; j += 4) {
            float4 av[4];
            #pragma unroll
            for (int a = 0; a < 4; ++a) av[a] = *(const float4*)&as_[ty * 4 + a][j];
            float4 bv[4];
            #pragma unroll
            for (int jj = 0; jj < 4; ++jj) bv[jj] = *(const float4*)&xs[j + jj][tx * 4];
            #pragma unroll
            for (int a = 0; a < 4; ++a) {
                acc[a][0] = fmaf(av[a].x, bv[0].x, acc[a][0]);
                acc[a][1] = fmaf(av[a].x, bv[0].y, acc[a][1]);
                acc[a][2] = fmaf(av[a].x, bv[0].z, acc[a][2]);
                acc[a][3] = fmaf(av[a].x, bv[0].w, acc[a][3]);
                acc[a][0] = fmaf(av[a].y, bv[1].x, acc[a][0]);
                acc[a][1] = fmaf(av[a].y, bv[1].y, acc[a][1]);
                acc[a][2] = fmaf(av[a].y, bv[1].z, acc[a][2]);
                acc[a][3] = fmaf(av[a].y, bv[1].w, acc[a][3]);
                acc[a][0] = fmaf(av[a].z, bv[2].x, acc[a][0]);
                acc[a][1] = fmaf(av[a].z, bv[2].y, acc[a][1]);
                acc[a][2] = fmaf(av[a].z, bv[2].z, acc[a][2]);
                acc[a][3] = fmaf(av[a].z, bv[2].w, acc[a][3]);
                acc[a][0] = fmaf(av[a].w, bv[3].x, acc[a][0]);
                acc[a][1] = fmaf(av[a].w, bv[3].y, acc[a][1]);
                acc[a][2] = fmaf(av[a].w, bv[3].z, acc[a][2]);
                acc[a][3] = fmaf(av[a].w, bv[3].w, acc[a][3]);
            }
        }
        __syncthreads();
    }
    #pragma unroll
    for (int a = 0; a < 4; ++a) {
        float4 o = make_float4(acc[a][0], acc[a][1], acc[a][2], acc[a][3]);
        *(float4*)&out[((size_t)b * kL + it * 64 + ty * 4 + a) * kD + h * 64 + tx * 4] = o;
    }
}

// ---------------------------------------------------------------------------
// K7: finalize loss (single block, deterministic reductions)
// ---------------------------------------------------------------------------
__global__ __launch_bounds__(1024) void k_loss(const float* __restrict__ spbuf,
        const float* __restrict__ entbuf, float* __restrict__ out_loss) {
    __shared__ float imps[kL * 3];
    __shared__ float red[1024];
    int tid = threadIdx.x;
    for (int idx = tid; idx < kL * 3; idx += 1024) {
        float s = 0.f;
        for (int bh = 0; bh < kBH; ++bh)
            s += spbuf[bh * kL * 3 + idx];
        imps[idx] = s;
    }
    float es = 0.f;
    for (int idx = tid; idx < kROWS; idx += 1024) es += entbuf[idx];
    red[tid] = es;
    __syncthreads();
    for (int s = 512; s > 0; s >>= 1) {
        if (tid < s) red[tid] += red[tid + s];
        __syncthreads();
    }
    float ent_total = red[0];
    __syncthreads();
    float ms = 0.f;
    for (int idx = tid; idx < kL * 3; idx += 1024) ms += imps[idx];
    red[tid] = ms;
    __syncthreads();
    for (int s = 512; s > 0; s >>= 1) {
        if (tid < s) red[tid] += red[tid + s];
        __syncthreads();
    }
    float mean = red[0] / (float)(kL * 3);
    __syncthreads();
    float vs = 0.f;
    for (int idx = tid; idx < kL * 3; idx += 1024) {
        float d = imps[idx] - mean;
        vs += d * d;
    }
    red[tid] = vs;
    __syncthreads();
    for (int s = 512; s > 0; s >>= 1) {
        if (tid < s) red[tid] += red[tid + s];
        __syncthreads();
    }
    if (tid == 0) {
        float var = red[0] / (float)(kL * 3 - 1);
        float loss_imp = var / (mean * mean + 1e-10f);
        float loss_dyn = -ent_total / (float)(kBH * 3);
        out_loss[0] = loss_imp + 0.1f * loss_dyn;
    }
}

// ---------------------------------------------------------------------------
extern "C" void kernel_launch(void* const* d_in, const int* in_sizes, int n_in,
                              void* d_out, int out_size, void* d_ws, size_t ws_size,
                              hipStream_t stream) {
    const float* x     = (const float*)d_in[0];
    const float* masks = (const float*)d_in[1];
    const float* W1    = (const float*)d_in[2];
    const float* b1    = (const float*)d_in[3];
    const float* W2    = (const float*)d_in[4];
    const float* b2    = (const float*)d_in[5];
    const float* Wg    = (const float*)d_in[6];
    const float* Wp    = (const float*)d_in[7];
    const float* bp    = (const float*)d_in[8];
    float* out = (float*)d_out;
    float* ws  = (float*)d_ws;

    float* adj    = ws;                       // 16,777,216
    float* q      = adj + 16777216;           //  2,097,152
    float* k      = q + 2097152;              //  2,097,152
    float* xp     = k + 2097152;              //  2,097,152
    float* spbuf  = xp + 2097152;             //     98,304
    float* entbuf = spbuf + 98304;            //     32,768

    k_qk<<<512, 256, 0, stream>>>(x, W1, b1, W2, b2, q, k);
    k_adj<<<kBH * 64, 256, 0, stream>>>(q, k, adj);
    k_select<<<kROWS / 4, 256, 0, stream>>>(adj, Wg, masks, spbuf, entbuf);
    k_xp<<<512, 256, 0, stream>>>(x, Wp, bp, xp);
    k_out<<<512, 256, 0, stream>>>(adj, xp, out);
    k_loss<<<1, 1024, 0, stream>>>(spbuf, entbuf, out + (size_t)kB * kL * kD);
}

// Round 4
// 178.930 us; speedup vs baseline: 2.7012x; 1.2145x over previous
//
#include <hip/hip_runtime.h>
#include <hip/hip_bf16.h>
#include <math.h>

// Problem constants
static constexpr int kB = 8;
static constexpr int kH = 8;
static constexpr int kL = 512;
static constexpr int kD = 512;
static constexpr int kDH = 64;     // D/H
static constexpr int kBH = 64;     // B*H
static constexpr int kROWS = kBH * kL;  // 32768

typedef short bf16x8 __attribute__((ext_vector_type(8)));
typedef float f32x4 __attribute__((ext_vector_type(4)));

__device__ __forceinline__ float gelu_exact(float v) {
    return 0.5f * v * (1.0f + erff(v * 0.70710678118654752440f));
}

// RNE float->bf16 (finite inputs only)
__device__ __forceinline__ ushort f2bf(float f) {
    unsigned u = __float_as_uint(f);
    unsigned r = u + 0x7fffu + ((u >> 16) & 1u);
    return (ushort)(r >> 16);
}

// ---------------------------------------------------------------------------
// K1: q = xh@W1^T + b1, k = xh@W2^T + b2 as tiled GEMM.
// ---------------------------------------------------------------------------
__global__ __launch_bounds__(256) void k_qk(const float* __restrict__ x,
        const float* __restrict__ W1, const float* __restrict__ b1,
        const float* __restrict__ W2, const float* __restrict__ b2,
        float* __restrict__ q, float* __restrict__ k) {
    int blk = blockIdx.x;              // b*64 + h*8 + lt
    int b = blk >> 6, h = (blk >> 3) & 7, lt = blk & 7;
    __shared__ float xt[64][68];       // [l][c]
    __shared__ float w1t[64][68];      // [d][c]
    __shared__ float w2t[64][68];
    int tid = threadIdx.x;
    #pragma unroll
    for (int r = 0; r < 16; ++r) {
        int e = tid + r * 256;
        int rr = e >> 6, cc = e & 63;
        xt[rr][cc]  = x[(b * kL + lt * 64 + rr) * kD + h * kDH + cc];
        w1t[rr][cc] = W1[rr * 64 + cc];
        w2t[rr][cc] = W2[rr * 64 + cc];
    }
    __syncthreads();
    int ty = tid >> 4, tx = tid & 15;
    float aq[4][4] = {}, ak[4][4] = {};
    #pragma unroll 2
    for (int c = 0; c < 64; c += 4) {
        float4 av[4], wq[4], wk[4];
        #pragma unroll
        for (int a = 0; a < 4; ++a) av[a] = *(const float4*)&xt[ty * 4 + a][c];
        #pragma unroll
        for (int j = 0; j < 4; ++j) {
            wq[j] = *(const float4*)&w1t[tx + 16 * j][c];
            wk[j] = *(const float4*)&w2t[tx + 16 * j][c];
        }
        #pragma unroll
        for (int a = 0; a < 4; ++a)
            #pragma unroll
            for (int j = 0; j < 4; ++j) {
                aq[a][j] = fmaf(av[a].x, wq[j].x, aq[a][j]);
                aq[a][j] = fmaf(av[a].y, wq[j].y, aq[a][j]);
                aq[a][j] = fmaf(av[a].z, wq[j].z, aq[a][j]);
                aq[a][j] = fmaf(av[a].w, wq[j].w, aq[a][j]);
                ak[a][j] = fmaf(av[a].x, wk[j].x, ak[a][j]);
                ak[a][j] = fmaf(av[a].y, wk[j].y, ak[a][j]);
                ak[a][j] = fmaf(av[a].z, wk[j].z, ak[a][j]);
                ak[a][j] = fmaf(av[a].w, wk[j].w, ak[a][j]);
            }
    }
    #pragma unroll
    for (int a = 0; a < 4; ++a)
        #pragma unroll
        for (int j = 0; j < 4; ++j) {
            int row = lt * 64 + ty * 4 + a;
            int col = tx + 16 * j;
            int o = ((b * kH + h) * kL + row) * kDH + col;
            q[o] = aq[a][j] + b1[col];
            k[o] = ak[a][j] + b2[col];
        }
}

// ---------------------------------------------------------------------------
// K2: adj = gelu(q @ k^T) per (b,h).  64x64 tile per block, K=64.
// ---------------------------------------------------------------------------
__global__ __launch_bounds__(256) void k_adj(const float* __restrict__ q,
        const float* __restrict__ k, float* __restrict__ adj) {
    int blk = blockIdx.x;
    int bh = blk >> 6;
    int it = (blk >> 3) & 7, jt = blk & 7;
    __shared__ float qs[64][68];
    __shared__ float ks[64][68];
    int tid = threadIdx.x;
    const float* qb = q + (bh * kL + it * 64) * kDH;
    const float* kb = k + (bh * kL + jt * 64) * kDH;
    #pragma unroll
    for (int r = 0; r < 16; ++r) {
        int e = tid + r * 256;
        int rr = e >> 6, cc = e & 63;
        qs[rr][cc] = qb[rr * 64 + cc];
        ks[rr][cc] = kb[rr * 64 + cc];
    }
    __syncthreads();
    int ty = tid >> 4, tx = tid & 15;
    float acc[4][4] = {};
    #pragma unroll 2
    for (int c = 0; c < 64; c += 4) {
        float4 av[4], bv[4];
        #pragma unroll
        for (int a = 0; a < 4; ++a) av[a] = *(const float4*)&qs[ty * 4 + a][c];
        #pragma unroll
        for (int j = 0; j < 4; ++j) bv[j] = *(const float4*)&ks[tx + 16 * j][c];
        #pragma unroll
        for (int a = 0; a < 4; ++a)
            #pragma unroll
            for (int j = 0; j < 4; ++j) {
                acc[a][j] = fmaf(av[a].x, bv[j].x, acc[a][j]);
                acc[a][j] = fmaf(av[a].y, bv[j].y, acc[a][j]);
                acc[a][j] = fmaf(av[a].z, bv[j].z, acc[a][j]);
                acc[a][j] = fmaf(av[a].w, bv[j].w, acc[a][j]);
            }
    }
    #pragma unroll
    for (int a = 0; a < 4; ++a)
        #pragma unroll
        for (int j = 0; j < 4; ++j) {
            int row = it * 64 + ty * 4 + a;
            int col = jt * 64 + tx + 16 * j;
            adj[((size_t)bh * kL + row) * kL + col] = gelu_exact(acc[a][j]);
        }
}

// ---------------------------------------------------------------------------
// K3 (fused): per-row, one wave:
//  - exact 256th-smallest via ballot/popcount bisection w/ early exit
//  - threshold; logits = row @ Wg^T; softmax-3; stable top-p -> gates
//  - mask build + diag, masked row softmax, L1 renorm, bf16 adjb write
// grid = ROWS/4 blocks of 256. Lane owns j = lane*8..+7.
// ---------------------------------------------------------------------------
__global__ __launch_bounds__(256) void k_select(const float* __restrict__ adj,
        const float* __restrict__ Wg, const float* __restrict__ masks,
        ushort* __restrict__ adjb,
        float* __restrict__ spbuf, float* __restrict__ entbuf) {
    int tid = threadIdx.x;
    int wave = tid >> 6, lane = tid & 63;
    int row = blockIdx.x * 4 + wave;
    int i = row & (kL - 1);
    const float* arow = adj + (size_t)row * kL;
    int j0 = lane * 8;

    float v[8];
    {
        float4 a0 = *(const float4*)&arow[j0];
        float4 a1 = *(const float4*)&arow[j0 + 4];
        v[0] = a0.x; v[1] = a0.y; v[2] = a0.z; v[3] = a0.w;
        v[4] = a1.x; v[5] = a1.y; v[6] = a1.z; v[7] = a1.w;
    }
    unsigned key[8];
    #pragma unroll
    for (int t = 0; t < 8; ++t) {
        unsigned u = __float_as_uint(v[t]);
        key[t] = (u & 0x80000000u) ? ~u : (u | 0x80000000u);
    }

    // exact k-th smallest (k=255 0-indexed): bisection, ballot counting.
    // invariant: kth key in [prefix, prefix+2^(bit+1)); cbp=#{key<prefix};
    // cin = #keys in interval. Early-exit when cin==1.
    unsigned prefix = 0;
    int cbp = 0, cin = 512;
    int bit = 31;
    while (cin > 1 && bit >= 0) {
        unsigned cand = prefix | (1u << bit);
        int c = 0;
        #pragma unroll
        for (int t = 0; t < 8; ++t)
            c += (int)__popcll(__ballot(key[t] < cand));
        if (255 < c) {
            cin = c - cbp;               // kth in [prefix, cand)
        } else {
            cin -= (c - cbp);            // kth in [cand, hi)
            prefix = cand;
            cbp = c;
        }
        --bit;
    }
    // extract kth key: unique key (or duplicated prefix) in [prefix, prefix+width)
    unsigned width = 1u << (bit + 1);
    unsigned kk2 = 0;
    #pragma unroll
    for (int t = 0; t < 8; ++t) {
        unsigned d = key[t] - prefix;
        if (d < width) kk2 = max(kk2, key[t]);
    }
    #pragma unroll
    for (int off = 1; off < 64; off <<= 1) kk2 = max(kk2, (unsigned)__shfl_xor((int)kk2, off));
    float thr = (kk2 & 0x80000000u) ? __uint_as_float(kk2 & 0x7fffffffu)
                                    : __uint_as_float(~kk2);

    // threshold + logits
    float l0 = 0.f, l1 = 0.f, l2 = 0.f;
    #pragma unroll
    for (int t = 0; t < 8; ++t) {
        float nv = (v[t] > thr) ? v[t] : 0.0f;
        v[t] = nv;
        int j = j0 + t;
        l0 = fmaf(nv, Wg[j], l0);
        l1 = fmaf(nv, Wg[kL + j], l1);
        l2 = fmaf(nv, Wg[2 * kL + j], l2);
    }
    #pragma unroll
    for (int off = 1; off < 64; off <<= 1) {
        l0 += __shfl_xor(l0, off);
        l1 += __shfl_xor(l1, off);
        l2 += __shfl_xor(l2, off);
    }
    // softmax-3 + stable top-p (all lanes redundantly; wave-uniform)
    float m = fmaxf(l0, fmaxf(l1, l2));
    float e0 = expf(l0 - m), e1 = expf(l1 - m), e2 = expf(l2 - m);
    float s = e0 + e1 + e2;
    float p[3] = {e0 / s, e1 / s, e2 / s};
    int o0, o1, o2;
    if (p[0] >= p[1] && p[0] >= p[2]) o0 = 0;
    else if (p[1] >= p[2]) o0 = 1;
    else o0 = 2;
    int r0 = (o0 == 0) ? 1 : 0;
    int r1 = (o0 == 2) ? 1 : 2;
    if (p[r0] >= p[r1]) { o1 = r0; o2 = r1; } else { o1 = r1; o2 = r0; }
    float sp0 = p[o0], sp1 = p[o1], sp2 = p[o2];
    float c0 = sp0, c1 = sp0 + sp1, c2 = c1 + sp2;
    bool m0 = c0 > 0.5f, m1 = c1 > 0.5f, m2 = c2 > 0.5f;
    int ti = m0 ? 0 : (m1 ? 1 : 2);
    bool mm0 = m0 && (ti != 0);
    bool mm1 = m1 && (ti != 1);
    bool mm2 = m2 && (ti != 2);
    float g[3] = {0.f, 0.f, 0.f};
    g[o0] = mm0 ? 0.f : 1.f;
    g[o1] = mm1 ? 0.f : 1.f;
    g[o2] = mm2 ? 0.f : 1.f;
    if (lane == 0) {
        spbuf[row * 3 + 0] = mm0 ? 0.f : sp0;
        spbuf[row * 3 + 1] = mm1 ? 0.f : sp1;
        spbuf[row * 3 + 2] = mm2 ? 0.f : sp2;
        entbuf[row] = p[0] * logf(p[0] + 1e-10f) +
                      p[1] * logf(p[1] + 1e-10f) +
                      p[2] * logf(p[2] + 1e-10f);
    }

    // mask build + diag, apply to thresholded values
    const float* mk0 = masks + (i * 3 + 0) * kL + j0;
    const float* mk1 = masks + (i * 3 + 1) * kL + j0;
    const float* mk2 = masks + (i * 3 + 2) * kL + j0;
    float av[8];
    #pragma unroll
    for (int half = 0; half < 2; ++half) {
        float4 v0 = *(const float4*)&mk0[half * 4];
        float4 v1 = *(const float4*)&mk1[half * 4];
        float4 v2 = *(const float4*)&mk2[half * 4];
        float mv[4];
        mv[0] = g[0] * v0.x + g[1] * v1.x + g[2] * v2.x;
        mv[1] = g[0] * v0.y + g[1] * v1.y + g[2] * v2.y;
        mv[2] = g[0] * v0.z + g[1] * v1.z + g[2] * v2.z;
        mv[3] = g[0] * v0.w + g[1] * v1.w + g[2] * v2.w;
        #pragma unroll
        for (int t = 0; t < 4; ++t) {
            int j = j0 + half * 4 + t;
            float mm = mv[t] + ((j == i) ? 1.0f : 0.0f);
            av[half * 4 + t] = v[half * 4 + t] * mm;
        }
    }
    // masked row softmax + L1 renorm
    float mx = av[0];
    #pragma unroll
    for (int t = 1; t < 8; ++t) mx = fmaxf(mx, av[t]);
    #pragma unroll
    for (int off = 1; off < 64; off <<= 1) mx = fmaxf(mx, __shfl_xor(mx, off));
    float e[8], ls = 0.f;
    #pragma unroll
    for (int t = 0; t < 8; ++t) { e[t] = expf(av[t] - mx); ls += e[t]; }
    #pragma unroll
    for (int off = 1; off < 64; off <<= 1) ls += __shfl_xor(ls, off);
    float inv = 1.0f / ls;
    float pp[8], l1s = 0.f;
    #pragma unroll
    for (int t = 0; t < 8; ++t) { pp[t] = e[t] * inv; l1s += fabsf(pp[t]); }
    #pragma unroll
    for (int off = 1; off < 64; off <<= 1) l1s += __shfl_xor(l1s, off);
    float s2 = 1.0f / fmaxf(l1s, 1e-12f);
    union { ushort u[8]; int4 vv; } pk;
    #pragma unroll
    for (int t = 0; t < 8; ++t) pk.u[t] = f2bf(pp[t] * s2);
    *(int4*)&adjb[(size_t)row * kL + j0] = pk.vv;
}

// ---------------------------------------------------------------------------
// K4: xp = x @ Wp^T + bp, output TRANSPOSED bf16: xpbT[dcol][b*L + l].
// grid = 64*8 = 512 blocks.
// ---------------------------------------------------------------------------
__global__ __launch_bounds__(256) void k_xp(const float* __restrict__ x,
        const float* __restrict__ Wp, const float* __restrict__ bp,
        ushort* __restrict__ xpbT) {
    int it = blockIdx.x >> 3, jt = blockIdx.x & 7;
    __shared__ float xs[64][68];
    __shared__ float ws[64][68];
    int tid = threadIdx.x;
    int ty = tid >> 4, tx = tid & 15;
    float acc[4][4] = {};
    for (int kb = 0; kb < 8; ++kb) {
        #pragma unroll
        for (int r = 0; r < 16; ++r) {
            int e = tid + r * 256;
            int rr = e >> 6, cc = e & 63;
            xs[rr][cc] = x[(it * 64 + rr) * kD + kb * 64 + cc];
            ws[rr][cc] = Wp[(jt * 64 + rr) * kD + kb * 64 + cc];
        }
        __syncthreads();
        #pragma unroll 2
        for (int c = 0; c < 64; c += 4) {
            float4 av[4], bv[4];
            #pragma unroll
            for (int a = 0; a < 4; ++a) av[a] = *(const float4*)&xs[ty * 4 + a][c];
            #pragma unroll
            for (int j = 0; j < 4; ++j) bv[j] = *(const float4*)&ws[tx + 16 * j][c];
            #pragma unroll
            for (int a = 0; a < 4; ++a)
                #pragma unroll
                for (int j = 0; j < 4; ++j) {
                    acc[a][j] = fmaf(av[a].x, bv[j].x, acc[a][j]);
                    acc[a][j] = fmaf(av[a].y, bv[j].y, acc[a][j]);
                    acc[a][j] = fmaf(av[a].z, bv[j].z, acc[a][j]);
                    acc[a][j] = fmaf(av[a].w, bv[j].w, acc[a][j]);
                }
        }
        __syncthreads();
    }
    // transpose via LDS (reuse xs): xs[dcol][l]
    #pragma unroll
    for (int a = 0; a < 4; ++a)
        #pragma unroll
        for (int j = 0; j < 4; ++j) {
            int dcol = tx + 16 * j;
            xs[dcol][ty * 4 + a] = acc[a][j] + bp[jt * 64 + dcol];
        }
    __syncthreads();
    int rr = tid >> 2, sg = tid & 3;
    union { ushort u[16]; int4 v[2]; } pk;
    #pragma unroll
    for (int u2 = 0; u2 < 16; ++u2)
        pk.u[u2] = f2bf(xs[rr][sg * 16 + u2]);
    size_t o = ((size_t)(jt * 64 + rr)) * (size_t)(kB * kL) + it * 64 + sg * 16;
    *(int4*)&xpbT[o] = pk.v[0];
    *(int4*)&xpbT[o + 8] = pk.v[1];
}

// ---------------------------------------------------------------------------
// K6 (MFMA): out[b, i, h*64+d] = sum_j adjb[bh,i,j] * xpbT[h*64+d][b*512+j]
// grid = B*H*8 = 512 blocks, 256 thr (4 waves). 64(i)x64(d) tile, K=512.
// Wave (wm,wn) owns 32x32; frags 16x16x32 bf16.
// ---------------------------------------------------------------------------
__global__ __launch_bounds__(256) void k_out(const ushort* __restrict__ adjb,
        const ushort* __restrict__ xpbT, float* __restrict__ out) {
    int blk = blockIdx.x;
    int bh = blk >> 3, it = blk & 7;
    int b = bh >> 3, h = bh & 7;
    __shared__ ushort as_[64][72];
    __shared__ ushort bs_[64][72];
    int tid = threadIdx.x;
    int lane = tid & 63, wave = tid >> 6;
    int wm = wave >> 1, wn = wave & 1;
    int r = tid >> 2, s = tid & 3;
    const ushort* aG = adjb + ((size_t)(bh * kL + it * 64 + r)) * kL + s * 16;
    const ushort* bG = xpbT + ((size_t)(h * kDH + r)) * (size_t)(kB * kL) + b * kL + s * 16;
    f32x4 acc[2][2] = {};
    int am = wm * 32 + (lane & 15);      // + fm*16
    int bn = wn * 32 + (lane & 15);      // + fn*16
    int coff = (lane >> 4) * 8;
    for (int kt = 0; kt < 8; ++kt) {
        int4 a0 = *(const int4*)(aG + kt * 64);
        int4 a1 = *(const int4*)(aG + kt * 64 + 8);
        int4 b0 = *(const int4*)(bG + kt * 64);
        int4 b1 = *(const int4*)(bG + kt * 64 + 8);
        __syncthreads();
        *(int4*)&as_[r][s * 16] = a0;
        *(int4*)&as_[r][s * 16 + 8] = a1;
        *(int4*)&bs_[r][s * 16] = b0;
        *(int4*)&bs_[r][s * 16 + 8] = b1;
        __syncthreads();
        #pragma unroll
        for (int kk = 0; kk < 2; ++kk) {
            bf16x8 af[2], bf[2];
            #pragma unroll
            for (int fm = 0; fm < 2; ++fm)
                af[fm] = *(const bf16x8*)&as_[am + fm * 16][kk * 32 + coff];
            #pragma unroll
            for (int fn = 0; fn < 2; ++fn)
                bf[fn] = *(const bf16x8*)&bs_[bn + fn * 16][kk * 32 + coff];
            #pragma unroll
            for (int fm = 0; fm < 2; ++fm)
                #pragma unroll
                for (int fn = 0; fn < 2; ++fn)
                    acc[fm][fn] = __builtin_amdgcn_mfma_f32_16x16x32_bf16(
                        af[fm], bf[fn], acc[fm][fn], 0, 0, 0);
        }
    }
    int mrow = it * 64 + wm * 32 + (lane >> 4) * 4;
    int ncol = h * kDH + wn * 32 + (lane & 15);
    #pragma unroll
    for (int fm = 0; fm < 2; ++fm)
        #pragma unroll
        for (int fn = 0; fn < 2; ++fn)
            #pragma unroll
            for (int rr = 0; rr < 4; ++rr)
                out[((size_t)b * kL + mrow + fm * 16 + rr) * kD + ncol + fn * 16] =
                    acc[fm][fn][rr];
}

// ---------------------------------------------------------------------------
// K7: finalize loss (single block, deterministic reductions)
// ---------------------------------------------------------------------------
__global__ __launch_bounds__(1024) void k_loss(const float* __restrict__ spbuf,
        const float* __restrict__ entbuf, float* __restrict__ out_loss) {
    __shared__ float imps[kL * 3];
    __shared__ float red[1024];
    int tid = threadIdx.x;
    for (int idx = tid; idx < kL * 3; idx += 1024) {
        float s = 0.f;
        for (int bh = 0; bh < kBH; ++bh)
            s += spbuf[bh * kL * 3 + idx];
        imps[idx] = s;
    }
    float es = 0.f;
    for (int idx = tid; idx < kROWS; idx += 1024) es += entbuf[idx];
    red[tid] = es;
    __syncthreads();
    for (int s = 512; s > 0; s >>= 1) {
        if (tid < s) red[tid] += red[tid + s];
        __syncthreads();
    }
    float ent_total = red[0];
    __syncthreads();
    float ms = 0.f;
    for (int idx = tid; idx < kL * 3; idx += 1024) ms += imps[idx];
    red[tid] = ms;
    __syncthreads();
    for (int s = 512; s > 0; s >>= 1) {
        if (tid < s) red[tid] += red[tid + s];
        __syncthreads();
    }
    float mean = red[0] / (float)(kL * 3);
    __syncthreads();
    float vs = 0.f;
    for (int idx = tid; idx < kL * 3; idx += 1024) {
        float d = imps[idx] - mean;
        vs += d * d;
    }
    red[tid] = vs;
    __syncthreads();
    for (int s = 512; s > 0; s >>= 1) {
        if (tid < s) red[tid] += red[tid + s];
        __syncthreads();
    }
    if (tid == 0) {
        float var = red[0] / (float)(kL * 3 - 1);
        float loss_imp = var / (mean * mean + 1e-10f);
        float loss_dyn = -ent_total / (float)(kBH * 3);
        out_loss[0] = loss_imp + 0.1f * loss_dyn;
    }
}

// ---------------------------------------------------------------------------
extern "C" void kernel_launch(void* const* d_in, const int* in_sizes, int n_in,
                              void* d_out, int out_size, void* d_ws, size_t ws_size,
                              hipStream_t stream) {
    const float* x     = (const float*)d_in[0];
    const float* masks = (const float*)d_in[1];
    const float* W1    = (const float*)d_in[2];
    const float* b1    = (const float*)d_in[3];
    const float* W2    = (const float*)d_in[4];
    const float* b2    = (const float*)d_in[5];
    const float* Wg    = (const float*)d_in[6];
    const float* Wp    = (const float*)d_in[7];
    const float* bp    = (const float*)d_in[8];
    float* out = (float*)d_out;
    float* ws  = (float*)d_ws;

    // workspace layout (float units). adjb overlays q,k (dead after k_adj;
    // stream order serializes k_adj -> k_select).
    float*  adj   = ws;                          // [0, 16777216)
    float*  q     = ws + 16777216;               // [16777216, 18874368)
    float*  k     = ws + 18874368;               // [18874368, 20971520)
    ushort* adjb  = (ushort*)(ws + 16777216);    // [16777216, 25165824) f-units
    ushort* xpbT  = (ushort*)(ws + 25165824);    // [25165824, 26214400) f-units
    float*  spbuf = ws + 26214400;               // 98,304
    float*  entbuf= ws + 26312704;               // 32,768

    k_qk<<<512, 256, 0, stream>>>(x, W1, b1, W2, b2, q, k);
    k_adj<<<kBH * 64, 256, 0, stream>>>(q, k, adj);
    k_select<<<kROWS / 4, 256, 0, stream>>>(adj, Wg, masks, adjb, spbuf, entbuf);
    k_xp<<<512, 256, 0, stream>>>(x, Wp, bp, xpbT);
    k_out<<<512, 256, 0, stream>>>(adjb, xpbT, out);
    k_loss<<<1, 1024, 0, stream>>>(spbuf, entbuf, out + (size_t)kB * kL * kD);
}

// Round 5
// 154.923 us; speedup vs baseline: 3.1198x; 1.1550x over previous
//
#include <hip/hip_runtime.h>
#include <hip/hip_bf16.h>
#include <math.h>

// Problem constants
static constexpr int kB = 8;
static constexpr int kH = 8;
static constexpr int kL = 512;
static constexpr int kD = 512;
static constexpr int kDH = 64;     // D/H
static constexpr int kBH = 64;     // B*H
static constexpr int kROWS = kBH * kL;  // 32768

typedef short bf16x8 __attribute__((ext_vector_type(8)));
typedef float f32x4 __attribute__((ext_vector_type(4)));

__device__ __forceinline__ float gelu_exact(float v) {
    return 0.5f * v * (1.0f + erff(v * 0.70710678118654752440f));
}

// RNE float->bf16 (finite inputs only)
__device__ __forceinline__ ushort f2bf(float f) {
    unsigned u = __float_as_uint(f);
    unsigned r = u + 0x7fffu + ((u >> 16) & 1u);
    return (ushort)(r >> 16);
}
__device__ __forceinline__ float bf2f(ushort h) {
    return __uint_as_float((unsigned)h << 16);
}

// ---------------------------------------------------------------------------
// K1: q = xh@W1^T + b1, k = xh@W2^T + b2 as tiled GEMM.
// ---------------------------------------------------------------------------
__global__ __launch_bounds__(256) void k_qk(const float* __restrict__ x,
        const float* __restrict__ W1, const float* __restrict__ b1,
        const float* __restrict__ W2, const float* __restrict__ b2,
        float* __restrict__ q, float* __restrict__ k) {
    int blk = blockIdx.x;              // b*64 + h*8 + lt
    int b = blk >> 6, h = (blk >> 3) & 7, lt = blk & 7;
    __shared__ float xt[64][68];       // [l][c]
    __shared__ float w1t[64][68];      // [d][c]
    __shared__ float w2t[64][68];
    int tid = threadIdx.x;
    #pragma unroll
    for (int r = 0; r < 16; ++r) {
        int e = tid + r * 256;
        int rr = e >> 6, cc = e & 63;
        xt[rr][cc]  = x[(b * kL + lt * 64 + rr) * kD + h * kDH + cc];
        w1t[rr][cc] = W1[rr * 64 + cc];
        w2t[rr][cc] = W2[rr * 64 + cc];
    }
    __syncthreads();
    int ty = tid >> 4, tx = tid & 15;
    float aq[4][4] = {}, ak[4][4] = {};
    #pragma unroll 2
    for (int c = 0; c < 64; c += 4) {
        float4 av[4], wq[4], wk[4];
        #pragma unroll
        for (int a = 0; a < 4; ++a) av[a] = *(const float4*)&xt[ty * 4 + a][c];
        #pragma unroll
        for (int j = 0; j < 4; ++j) {
            wq[j] = *(const float4*)&w1t[tx + 16 * j][c];
            wk[j] = *(const float4*)&w2t[tx + 16 * j][c];
        }
        #pragma unroll
        for (int a = 0; a < 4; ++a)
            #pragma unroll
            for (int j = 0; j < 4; ++j) {
                aq[a][j] = fmaf(av[a].x, wq[j].x, aq[a][j]);
                aq[a][j] = fmaf(av[a].y, wq[j].y, aq[a][j]);
                aq[a][j] = fmaf(av[a].z, wq[j].z, aq[a][j]);
                aq[a][j] = fmaf(av[a].w, wq[j].w, aq[a][j]);
                ak[a][j] = fmaf(av[a].x, wk[j].x, ak[a][j]);
                ak[a][j] = fmaf(av[a].y, wk[j].y, ak[a][j]);
                ak[a][j] = fmaf(av[a].z, wk[j].z, ak[a][j]);
                ak[a][j] = fmaf(av[a].w, wk[j].w, ak[a][j]);
            }
    }
    #pragma unroll
    for (int a = 0; a < 4; ++a)
        #pragma unroll
        for (int j = 0; j < 4; ++j) {
            int row = lt * 64 + ty * 4 + a;
            int col = tx + 16 * j;
            int o = ((b * kH + h) * kL + row) * kDH + col;
            q[o] = aq[a][j] + b1[col];
            k[o] = ak[a][j] + b2[col];
        }
}

// ---------------------------------------------------------------------------
// K2 (MFMA, split-bf16): adj = gelu(q @ k^T) per (b,h). 64x64 tile, K=64.
// q,k staged fp32->hi/lo bf16 in LDS; S = hi*hi + hi*lo + lo*hi (err ~1e-5).
// grid = B*H*8*8 = 4096, 256 thr (4 waves, 2x2 of 32x32).
// ---------------------------------------------------------------------------
__global__ __launch_bounds__(256) void k_adj(const float* __restrict__ q,
        const float* __restrict__ k, float* __restrict__ adj) {
    int blk = blockIdx.x;
    int bh = blk >> 6;
    int it = (blk >> 3) & 7, jt = blk & 7;
    __shared__ ushort ah[64][72], al[64][72];
    __shared__ ushort bh_[64][72], bl[64][72];
    int tid = threadIdx.x;
    int r = tid >> 2, s = tid & 3;
    const float* qb = q + (size_t)(bh * kL + it * 64 + r) * kDH + s * 16;
    const float* kb = k + (size_t)(bh * kL + jt * 64 + r) * kDH + s * 16;
    // stage both tiles: fp32 -> (hi, lo) bf16
    #pragma unroll
    for (int tsel = 0; tsel < 2; ++tsel) {
        const float* src = tsel ? kb : qb;
        union { ushort u[16]; int4 v[2]; } ph, pl;
        #pragma unroll
        for (int c4 = 0; c4 < 4; ++c4) {
            float4 f = *(const float4*)(src + c4 * 4);
            float fv[4] = {f.x, f.y, f.z, f.w};
            #pragma unroll
            for (int t = 0; t < 4; ++t) {
                ushort hh = f2bf(fv[t]);
                ph.u[c4 * 4 + t] = hh;
                pl.u[c4 * 4 + t] = f2bf(fv[t] - bf2f(hh));
            }
        }
        if (tsel == 0) {
            *(int4*)&ah[r][s * 16] = ph.v[0];
            *(int4*)&ah[r][s * 16 + 8] = ph.v[1];
            *(int4*)&al[r][s * 16] = pl.v[0];
            *(int4*)&al[r][s * 16 + 8] = pl.v[1];
        } else {
            *(int4*)&bh_[r][s * 16] = ph.v[0];
            *(int4*)&bh_[r][s * 16 + 8] = ph.v[1];
            *(int4*)&bl[r][s * 16] = pl.v[0];
            *(int4*)&bl[r][s * 16 + 8] = pl.v[1];
        }
    }
    __syncthreads();
    int lane = tid & 63, wave = tid >> 6;
    int wm = wave >> 1, wn = wave & 1;
    int am = wm * 32 + (lane & 15);
    int bn = wn * 32 + (lane & 15);
    int coff = (lane >> 4) * 8;
    f32x4 acc[2][2] = {};
    #pragma unroll
    for (int kk = 0; kk < 2; ++kk) {
        bf16x8 afh[2], afl[2], bfh[2], bfl[2];
        #pragma unroll
        for (int fm = 0; fm < 2; ++fm) {
            afh[fm] = *(const bf16x8*)&ah[am + fm * 16][kk * 32 + coff];
            afl[fm] = *(const bf16x8*)&al[am + fm * 16][kk * 32 + coff];
        }
        #pragma unroll
        for (int fn = 0; fn < 2; ++fn) {
            bfh[fn] = *(const bf16x8*)&bh_[bn + fn * 16][kk * 32 + coff];
            bfl[fn] = *(const bf16x8*)&bl[bn + fn * 16][kk * 32 + coff];
        }
        #pragma unroll
        for (int fm = 0; fm < 2; ++fm)
            #pragma unroll
            for (int fn = 0; fn < 2; ++fn) {
                acc[fm][fn] = __builtin_amdgcn_mfma_f32_16x16x32_bf16(
                    afh[fm], bfh[fn], acc[fm][fn], 0, 0, 0);
                acc[fm][fn] = __builtin_amdgcn_mfma_f32_16x16x32_bf16(
                    afh[fm], bfl[fn], acc[fm][fn], 0, 0, 0);
                acc[fm][fn] = __builtin_amdgcn_mfma_f32_16x16x32_bf16(
                    afl[fm], bfh[fn], acc[fm][fn], 0, 0, 0);
            }
    }
    int mrow = it * 64 + wm * 32 + (lane >> 4) * 4;
    int ncol = jt * 64 + wn * 32 + (lane & 15);
    #pragma unroll
    for (int fm = 0; fm < 2; ++fm)
        #pragma unroll
        for (int fn = 0; fn < 2; ++fn)
            #pragma unroll
            for (int rr = 0; rr < 4; ++rr)
                adj[((size_t)bh * kL + mrow + fm * 16 + rr) * kL + ncol + fn * 16] =
                    gelu_exact(acc[fm][fn][rr]);
}

// ---------------------------------------------------------------------------
// K3 (fused): per-row, one wave:
//  - exact 256th-smallest via ballot/popcount bisection w/ early exit
//  - threshold; logits = row @ Wg^T; softmax-3; stable top-p -> gates
//  - mask build + diag, masked row softmax, L1 renorm, bf16 adjb write
// grid = ROWS/4 blocks of 256. Lane owns j = lane*8..+7.
// ---------------------------------------------------------------------------
__global__ __launch_bounds__(256) void k_select(const float* __restrict__ adj,
        const float* __restrict__ Wg, const float* __restrict__ masks,
        ushort* __restrict__ adjb,
        float* __restrict__ spbuf, float* __restrict__ entbuf) {
    int tid = threadIdx.x;
    int wave = tid >> 6, lane = tid & 63;
    int row = blockIdx.x * 4 + wave;
    int i = row & (kL - 1);
    const float* arow = adj + (size_t)row * kL;
    int j0 = lane * 8;

    float v[8];
    {
        float4 a0 = *(const float4*)&arow[j0];
        float4 a1 = *(const float4*)&arow[j0 + 4];
        v[0] = a0.x; v[1] = a0.y; v[2] = a0.z; v[3] = a0.w;
        v[4] = a1.x; v[5] = a1.y; v[6] = a1.z; v[7] = a1.w;
    }
    unsigned key[8];
    #pragma unroll
    for (int t = 0; t < 8; ++t) {
        unsigned u = __float_as_uint(v[t]);
        key[t] = (u & 0x80000000u) ? ~u : (u | 0x80000000u);
    }

    // exact k-th smallest (k=255 0-indexed): bisection, ballot counting.
    unsigned prefix = 0;
    int cbp = 0, cin = 512;
    int bit = 31;
    while (cin > 1 && bit >= 0) {
        unsigned cand = prefix | (1u << bit);
        int c = 0;
        #pragma unroll
        for (int t = 0; t < 8; ++t)
            c += (int)__popcll(__ballot(key[t] < cand));
        if (255 < c) {
            cin = c - cbp;               // kth in [prefix, cand)
        } else {
            cin -= (c - cbp);            // kth in [cand, hi)
            prefix = cand;
            cbp = c;
        }
        --bit;
    }
    unsigned width = 1u << (bit + 1);
    unsigned kk2 = 0;
    #pragma unroll
    for (int t = 0; t < 8; ++t) {
        unsigned d = key[t] - prefix;
        if (d < width) kk2 = max(kk2, key[t]);
    }
    #pragma unroll
    for (int off = 1; off < 64; off <<= 1) kk2 = max(kk2, (unsigned)__shfl_xor((int)kk2, off));
    float thr = (kk2 & 0x80000000u) ? __uint_as_float(kk2 & 0x7fffffffu)
                                    : __uint_as_float(~kk2);

    // threshold + logits
    float l0 = 0.f, l1 = 0.f, l2 = 0.f;
    #pragma unroll
    for (int t = 0; t < 8; ++t) {
        float nv = (v[t] > thr) ? v[t] : 0.0f;
        v[t] = nv;
        int j = j0 + t;
        l0 = fmaf(nv, Wg[j], l0);
        l1 = fmaf(nv, Wg[kL + j], l1);
        l2 = fmaf(nv, Wg[2 * kL + j], l2);
    }
    #pragma unroll
    for (int off = 1; off < 64; off <<= 1) {
        l0 += __shfl_xor(l0, off);
        l1 += __shfl_xor(l1, off);
        l2 += __shfl_xor(l2, off);
    }
    // softmax-3 + stable top-p (all lanes redundantly; wave-uniform)
    float m = fmaxf(l0, fmaxf(l1, l2));
    float e0 = expf(l0 - m), e1 = expf(l1 - m), e2 = expf(l2 - m);
    float s = e0 + e1 + e2;
    float p[3] = {e0 / s, e1 / s, e2 / s};
    int o0, o1, o2;
    if (p[0] >= p[1] && p[0] >= p[2]) o0 = 0;
    else if (p[1] >= p[2]) o0 = 1;
    else o0 = 2;
    int r0 = (o0 == 0) ? 1 : 0;
    int r1 = (o0 == 2) ? 1 : 2;
    if (p[r0] >= p[r1]) { o1 = r0; o2 = r1; } else { o1 = r1; o2 = r0; }
    float sp0 = p[o0], sp1 = p[o1], sp2 = p[o2];
    float c0 = sp0, c1 = sp0 + sp1, c2 = c1 + sp2;
    bool m0 = c0 > 0.5f, m1 = c1 > 0.5f, m2 = c2 > 0.5f;
    int ti = m0 ? 0 : (m1 ? 1 : 2);
    bool mm0 = m0 && (ti != 0);
    bool mm1 = m1 && (ti != 1);
    bool mm2 = m2 && (ti != 2);
    float g[3] = {0.f, 0.f, 0.f};
    g[o0] = mm0 ? 0.f : 1.f;
    g[o1] = mm1 ? 0.f : 1.f;
    g[o2] = mm2 ? 0.f : 1.f;
    if (lane == 0) {
        spbuf[row * 3 + 0] = mm0 ? 0.f : sp0;
        spbuf[row * 3 + 1] = mm1 ? 0.f : sp1;
        spbuf[row * 3 + 2] = mm2 ? 0.f : sp2;
        entbuf[row] = p[0] * logf(p[0] + 1e-10f) +
                      p[1] * logf(p[1] + 1e-10f) +
                      p[2] * logf(p[2] + 1e-10f);
    }

    // mask build + diag, apply to thresholded values
    const float* mk0 = masks + (i * 3 + 0) * kL + j0;
    const float* mk1 = masks + (i * 3 + 1) * kL + j0;
    const float* mk2 = masks + (i * 3 + 2) * kL + j0;
    float av[8];
    #pragma unroll
    for (int half = 0; half < 2; ++half) {
        float4 v0 = *(const float4*)&mk0[half * 4];
        float4 v1 = *(const float4*)&mk1[half * 4];
        float4 v2 = *(const float4*)&mk2[half * 4];
        float mv[4];
        mv[0] = g[0] * v0.x + g[1] * v1.x + g[2] * v2.x;
        mv[1] = g[0] * v0.y + g[1] * v1.y + g[2] * v2.y;
        mv[2] = g[0] * v0.z + g[1] * v1.z + g[2] * v2.z;
        mv[3] = g[0] * v0.w + g[1] * v1.w + g[2] * v2.w;
        #pragma unroll
        for (int t = 0; t < 4; ++t) {
            int j = j0 + half * 4 + t;
            float mm = mv[t] + ((j == i) ? 1.0f : 0.0f);
            av[half * 4 + t] = v[half * 4 + t] * mm;
        }
    }
    // masked row softmax + L1 renorm
    float mx = av[0];
    #pragma unroll
    for (int t = 1; t < 8; ++t) mx = fmaxf(mx, av[t]);
    #pragma unroll
    for (int off = 1; off < 64; off <<= 1) mx = fmaxf(mx, __shfl_xor(mx, off));
    float e[8], ls = 0.f;
    #pragma unroll
    for (int t = 0; t < 8; ++t) { e[t] = expf(av[t] - mx); ls += e[t]; }
    #pragma unroll
    for (int off = 1; off < 64; off <<= 1) ls += __shfl_xor(ls, off);
    float inv = 1.0f / ls;
    float pp[8], l1s = 0.f;
    #pragma unroll
    for (int t = 0; t < 8; ++t) { pp[t] = e[t] * inv; l1s += fabsf(pp[t]); }
    #pragma unroll
    for (int off = 1; off < 64; off <<= 1) l1s += __shfl_xor(l1s, off);
    float s2 = 1.0f / fmaxf(l1s, 1e-12f);
    union { ushort u[8]; int4 vv; } pk;
    #pragma unroll
    for (int t = 0; t < 8; ++t) pk.u[t] = f2bf(pp[t] * s2);
    *(int4*)&adjb[(size_t)row * kL + j0] = pk.vv;
}

// ---------------------------------------------------------------------------
// K4: xp = x @ Wp^T + bp, output TRANSPOSED bf16: xpbT[dcol][b*L + l].
// ---------------------------------------------------------------------------
__global__ __launch_bounds__(256) void k_xp(const float* __restrict__ x,
        const float* __restrict__ Wp, const float* __restrict__ bp,
        ushort* __restrict__ xpbT) {
    int it = blockIdx.x >> 3, jt = blockIdx.x & 7;
    __shared__ float xs[64][68];
    __shared__ float ws[64][68];
    int tid = threadIdx.x;
    int ty = tid >> 4, tx = tid & 15;
    float acc[4][4] = {};
    for (int kb = 0; kb < 8; ++kb) {
        #pragma unroll
        for (int r = 0; r < 16; ++r) {
            int e = tid + r * 256;
            int rr = e >> 6, cc = e & 63;
            xs[rr][cc] = x[(it * 64 + rr) * kD + kb * 64 + cc];
            ws[rr][cc] = Wp[(jt * 64 + rr) * kD + kb * 64 + cc];
        }
        __syncthreads();
        #pragma unroll 2
        for (int c = 0; c < 64; c += 4) {
            float4 av[4], bv[4];
            #pragma unroll
            for (int a = 0; a < 4; ++a) av[a] = *(const float4*)&xs[ty * 4 + a][c];
            #pragma unroll
            for (int j = 0; j < 4; ++j) bv[j] = *(const float4*)&ws[tx + 16 * j][c];
            #pragma unroll
            for (int a = 0; a < 4; ++a)
                #pragma unroll
                for (int j = 0; j < 4; ++j) {
                    acc[a][j] = fmaf(av[a].x, bv[j].x, acc[a][j]);
                    acc[a][j] = fmaf(av[a].y, bv[j].y, acc[a][j]);
                    acc[a][j] = fmaf(av[a].z, bv[j].z, acc[a][j]);
                    acc[a][j] = fmaf(av[a].w, bv[j].w, acc[a][j]);
                }
        }
        __syncthreads();
    }
    // transpose via LDS (reuse xs): xs[dcol][l]
    #pragma unroll
    for (int a = 0; a < 4; ++a)
        #pragma unroll
        for (int j = 0; j < 4; ++j) {
            int dcol = tx + 16 * j;
            xs[dcol][ty * 4 + a] = acc[a][j] + bp[jt * 64 + dcol];
        }
    __syncthreads();
    int rr = tid >> 2, sg = tid & 3;
    union { ushort u[16]; int4 v[2]; } pk;
    #pragma unroll
    for (int u2 = 0; u2 < 16; ++u2)
        pk.u[u2] = f2bf(xs[rr][sg * 16 + u2]);
    size_t o = ((size_t)(jt * 64 + rr)) * (size_t)(kB * kL) + it * 64 + sg * 16;
    *(int4*)&xpbT[o] = pk.v[0];
    *(int4*)&xpbT[o + 8] = pk.v[1];
}

// ---------------------------------------------------------------------------
// K6 (MFMA): out[b, i, h*64+d] = sum_j adjb[bh,i,j] * xpbT[h*64+d][b*512+j]
// ---------------------------------------------------------------------------
__global__ __launch_bounds__(256) void k_out(const ushort* __restrict__ adjb,
        const ushort* __restrict__ xpbT, float* __restrict__ out) {
    int blk = blockIdx.x;
    int bh = blk >> 3, it = blk & 7;
    int b = bh >> 3, h = bh & 7;
    __shared__ ushort as_[64][72];
    __shared__ ushort bs_[64][72];
    int tid = threadIdx.x;
    int lane = tid & 63, wave = tid >> 6;
    int wm = wave >> 1, wn = wave & 1;
    int r = tid >> 2, s = tid & 3;
    const ushort* aG = adjb + ((size_t)(bh * kL + it * 64 + r)) * kL + s * 16;
    const ushort* bG = xpbT + ((size_t)(h * kDH + r)) * (size_t)(kB * kL) + b * kL + s * 16;
    f32x4 acc[2][2] = {};
    int am = wm * 32 + (lane & 15);
    int bn = wn * 32 + (lane & 15);
    int coff = (lane >> 4) * 8;
    for (int kt = 0; kt < 8; ++kt) {
        int4 a0 = *(const int4*)(aG + kt * 64);
        int4 a1 = *(const int4*)(aG + kt * 64 + 8);
        int4 b0 = *(const int4*)(bG + kt * 64);
        int4 b1 = *(const int4*)(bG + kt * 64 + 8);
        __syncthreads();
        *(int4*)&as_[r][s * 16] = a0;
        *(int4*)&as_[r][s * 16 + 8] = a1;
        *(int4*)&bs_[r][s * 16] = b0;
        *(int4*)&bs_[r][s * 16 + 8] = b1;
        __syncthreads();
        #pragma unroll
        for (int kk = 0; kk < 2; ++kk) {
            bf16x8 af[2], bf[2];
            #pragma unroll
            for (int fm = 0; fm < 2; ++fm)
                af[fm] = *(const bf16x8*)&as_[am + fm * 16][kk * 32 + coff];
            #pragma unroll
            for (int fn = 0; fn < 2; ++fn)
                bf[fn] = *(const bf16x8*)&bs_[bn + fn * 16][kk * 32 + coff];
            #pragma unroll
            for (int fm = 0; fm < 2; ++fm)
                #pragma unroll
                for (int fn = 0; fn < 2; ++fn)
                    acc[fm][fn] = __builtin_amdgcn_mfma_f32_16x16x32_bf16(
                        af[fm], bf[fn], acc[fm][fn], 0, 0, 0);
        }
    }
    int mrow = it * 64 + wm * 32 + (lane >> 4) * 4;
    int ncol = h * kDH + wn * 32 + (lane & 15);
    #pragma unroll
    for (int fm = 0; fm < 2; ++fm)
        #pragma unroll
        for (int fn = 0; fn < 2; ++fn)
            #pragma unroll
            for (int rr = 0; rr < 4; ++rr)
                out[((size_t)b * kL + mrow + fm * 16 + rr) * kD + ncol + fn * 16] =
                    acc[fm][fn][rr];
}

// ---------------------------------------------------------------------------
// K7: finalize loss (single block, deterministic reductions)
// ---------------------------------------------------------------------------
__global__ __launch_bounds__(1024) void k_loss(const float* __restrict__ spbuf,
        const float* __restrict__ entbuf, float* __restrict__ out_loss) {
    __shared__ float imps[kL * 3];
    __shared__ float red[1024];
    int tid = threadIdx.x;
    for (int idx = tid; idx < kL * 3; idx += 1024) {
        float s = 0.f;
        for (int bh = 0; bh < kBH; ++bh)
            s += spbuf[bh * kL * 3 + idx];
        imps[idx] = s;
    }
    float es = 0.f;
    for (int idx = tid; idx < kROWS; idx += 1024) es += entbuf[idx];
    red[tid] = es;
    __syncthreads();
    for (int s = 512; s > 0; s >>= 1) {
        if (tid < s) red[tid] += red[tid + s];
        __syncthreads();
    }
    float ent_total = red[0];
    __syncthreads();
    float ms = 0.f;
    for (int idx = tid; idx < kL * 3; idx += 1024) ms += imps[idx];
    red[tid] = ms;
    __syncthreads();
    for (int s = 512; s > 0; s >>= 1) {
        if (tid < s) red[tid] += red[tid + s];
        __syncthreads();
    }
    float mean = red[0] / (float)(kL * 3);
    __syncthreads();
    float vs = 0.f;
    for (int idx = tid; idx < kL * 3; idx += 1024) {
        float d = imps[idx] - mean;
        vs += d * d;
    }
    red[tid] = vs;
    __syncthreads();
    for (int s = 512; s > 0; s >>= 1) {
        if (tid < s) red[tid] += red[tid + s];
        __syncthreads();
    }
    if (tid == 0) {
        float var = red[0] / (float)(kL * 3 - 1);
        float loss_imp = var / (mean * mean + 1e-10f);
        float loss_dyn = -ent_total / (float)(kBH * 3);
        out_loss[0] = loss_imp + 0.1f * loss_dyn;
    }
}

// ---------------------------------------------------------------------------
extern "C" void kernel_launch(void* const* d_in, const int* in_sizes, int n_in,
                              void* d_out, int out_size, void* d_ws, size_t ws_size,
                              hipStream_t stream) {
    const float* x     = (const float*)d_in[0];
    const float* masks = (const float*)d_in[1];
    const float* W1    = (const float*)d_in[2];
    const float* b1    = (const float*)d_in[3];
    const float* W2    = (const float*)d_in[4];
    const float* b2    = (const float*)d_in[5];
    const float* Wg    = (const float*)d_in[6];
    const float* Wp    = (const float*)d_in[7];
    const float* bp    = (const float*)d_in[8];
    float* out = (float*)d_out;
    float* ws  = (float*)d_ws;

    // workspace layout (float units). adjb overlays q,k (dead after k_adj;
    // stream order serializes k_adj -> k_select).
    float*  adj   = ws;                          // [0, 16777216)
    float*  q     = ws + 16777216;               // [16777216, 18874368)
    float*  k     = ws + 18874368;               // [18874368, 20971520)
    ushort* adjb  = (ushort*)(ws + 16777216);    // [16777216, 25165824) f-units
    ushort* xpbT  = (ushort*)(ws + 25165824);    // [25165824, 26214400) f-units
    float*  spbuf = ws + 26214400;               // 98,304
    float*  entbuf= ws + 26312704;               // 32,768

    k_qk<<<512, 256, 0, stream>>>(x, W1, b1, W2, b2, q, k);
    k_adj<<<kBH * 64, 256, 0, stream>>>(q, k, adj);
    k_select<<<kROWS / 4, 256, 0, stream>>>(adj, Wg, masks, adjb, spbuf, entbuf);
    k_xp<<<512, 256, 0, stream>>>(x, Wp, bp, xpbT);
    k_out<<<512, 256, 0, stream>>>(adjb, xpbT, out);
    k_loss<<<1, 1024, 0, stream>>>(spbuf, entbuf, out + (size_t)kB * kL * kD);
}

// Round 6
// 130.169 us; speedup vs baseline: 3.7131x; 1.1902x over previous
//
#include <hip/hip_runtime.h>
#include <hip/hip_bf16.h>
#include <math.h>

// Problem constants
static constexpr int kB = 8;
static constexpr int kH = 8;
static constexpr int kL = 512;
static constexpr int kD = 512;
static constexpr int kDH = 64;     // D/H
static constexpr int kBH = 64;     // B*H
static constexpr int kROWS = kBH * kL;  // 32768

typedef short bf16x8 __attribute__((ext_vector_type(8)));
typedef float f32x4 __attribute__((ext_vector_type(4)));

__device__ __forceinline__ float gelu_exact(float v) {
    return 0.5f * v * (1.0f + erff(v * 0.70710678118654752440f));
}

// RNE float->bf16 (finite inputs only)
__device__ __forceinline__ ushort f2bf(float f) {
    unsigned u = __float_as_uint(f);
    unsigned r = u + 0x7fffu + ((u >> 16) & 1u);
    return (ushort)(r >> 16);
}
__device__ __forceinline__ float bf2f(ushort h) {
    return __uint_as_float((unsigned)h << 16);
}

// ---------------------------------------------------------------------------
// K1: q = xh@W1^T + b1, k = xh@W2^T + b2 as tiled GEMM.
// ---------------------------------------------------------------------------
__global__ __launch_bounds__(256) void k_qk(const float* __restrict__ x,
        const float* __restrict__ W1, const float* __restrict__ b1,
        const float* __restrict__ W2, const float* __restrict__ b2,
        float* __restrict__ q, float* __restrict__ k) {
    int blk = blockIdx.x;              // b*64 + h*8 + lt
    int b = blk >> 6, h = (blk >> 3) & 7, lt = blk & 7;
    __shared__ float xt[64][68];       // [l][c]
    __shared__ float w1t[64][68];      // [d][c]
    __shared__ float w2t[64][68];
    int tid = threadIdx.x;
    #pragma unroll
    for (int r = 0; r < 16; ++r) {
        int e = tid + r * 256;
        int rr = e >> 6, cc = e & 63;
        xt[rr][cc]  = x[(b * kL + lt * 64 + rr) * kD + h * kDH + cc];
        w1t[rr][cc] = W1[rr * 64 + cc];
        w2t[rr][cc] = W2[rr * 64 + cc];
    }
    __syncthreads();
    int ty = tid >> 4, tx = tid & 15;
    float aq[4][4] = {}, ak[4][4] = {};
    #pragma unroll 2
    for (int c = 0; c < 64; c += 4) {
        float4 av[4], wq[4], wk[4];
        #pragma unroll
        for (int a = 0; a < 4; ++a) av[a] = *(const float4*)&xt[ty * 4 + a][c];
        #pragma unroll
        for (int j = 0; j < 4; ++j) {
            wq[j] = *(const float4*)&w1t[tx + 16 * j][c];
            wk[j] = *(const float4*)&w2t[tx + 16 * j][c];
        }
        #pragma unroll
        for (int a = 0; a < 4; ++a)
            #pragma unroll
            for (int j = 0; j < 4; ++j) {
                aq[a][j] = fmaf(av[a].x, wq[j].x, aq[a][j]);
                aq[a][j] = fmaf(av[a].y, wq[j].y, aq[a][j]);
                aq[a][j] = fmaf(av[a].z, wq[j].z, aq[a][j]);
                aq[a][j] = fmaf(av[a].w, wq[j].w, aq[a][j]);
                ak[a][j] = fmaf(av[a].x, wk[j].x, ak[a][j]);
                ak[a][j] = fmaf(av[a].y, wk[j].y, ak[a][j]);
                ak[a][j] = fmaf(av[a].z, wk[j].z, ak[a][j]);
                ak[a][j] = fmaf(av[a].w, wk[j].w, ak[a][j]);
            }
    }
    #pragma unroll
    for (int a = 0; a < 4; ++a)
        #pragma unroll
        for (int j = 0; j < 4; ++j) {
            int row = lt * 64 + ty * 4 + a;
            int col = tx + 16 * j;
            int o = ((b * kH + h) * kL + row) * kDH + col;
            q[o] = aq[a][j] + b1[col];
            k[o] = ak[a][j] + b2[col];
        }
}

// ---------------------------------------------------------------------------
// K2 (MFMA, split-bf16): adj = gelu(q @ k^T) per (b,h). 64x64 tile, K=64.
// q,k staged fp32->hi/lo bf16 in LDS; S = hi*hi + hi*lo + lo*hi (err ~1e-5).
// grid = B*H*8*8 = 4096, 256 thr (4 waves, 2x2 of 32x32).
// ---------------------------------------------------------------------------
__global__ __launch_bounds__(256) void k_adj(const float* __restrict__ q,
        const float* __restrict__ k, float* __restrict__ adj) {
    int blk = blockIdx.x;
    int bh = blk >> 6;
    int it = (blk >> 3) & 7, jt = blk & 7;
    __shared__ ushort ah[64][72], al[64][72];
    __shared__ ushort bh_[64][72], bl[64][72];
    int tid = threadIdx.x;
    int r = tid >> 2, s = tid & 3;
    const float* qb = q + (size_t)(bh * kL + it * 64 + r) * kDH + s * 16;
    const float* kb = k + (size_t)(bh * kL + jt * 64 + r) * kDH + s * 16;
    // stage both tiles: fp32 -> (hi, lo) bf16
    #pragma unroll
    for (int tsel = 0; tsel < 2; ++tsel) {
        const float* src = tsel ? kb : qb;
        union { ushort u[16]; int4 v[2]; } ph, pl;
        #pragma unroll
        for (int c4 = 0; c4 < 4; ++c4) {
            float4 f = *(const float4*)(src + c4 * 4);
            float fv[4] = {f.x, f.y, f.z, f.w};
            #pragma unroll
            for (int t = 0; t < 4; ++t) {
                ushort hh = f2bf(fv[t]);
                ph.u[c4 * 4 + t] = hh;
                pl.u[c4 * 4 + t] = f2bf(fv[t] - bf2f(hh));
            }
        }
        if (tsel == 0) {
            *(int4*)&ah[r][s * 16] = ph.v[0];
            *(int4*)&ah[r][s * 16 + 8] = ph.v[1];
            *(int4*)&al[r][s * 16] = pl.v[0];
            *(int4*)&al[r][s * 16 + 8] = pl.v[1];
        } else {
            *(int4*)&bh_[r][s * 16] = ph.v[0];
            *(int4*)&bh_[r][s * 16 + 8] = ph.v[1];
            *(int4*)&bl[r][s * 16] = pl.v[0];
            *(int4*)&bl[r][s * 16 + 8] = pl.v[1];
        }
    }
    __syncthreads();
    int lane = tid & 63, wave = tid >> 6;
    int wm = wave >> 1, wn = wave & 1;
    int am = wm * 32 + (lane & 15);
    int bn = wn * 32 + (lane & 15);
    int coff = (lane >> 4) * 8;
    f32x4 acc[2][2] = {};
    #pragma unroll
    for (int kk = 0; kk < 2; ++kk) {
        bf16x8 afh[2], afl[2], bfh[2], bfl[2];
        #pragma unroll
        for (int fm = 0; fm < 2; ++fm) {
            afh[fm] = *(const bf16x8*)&ah[am + fm * 16][kk * 32 + coff];
            afl[fm] = *(const bf16x8*)&al[am + fm * 16][kk * 32 + coff];
        }
        #pragma unroll
        for (int fn = 0; fn < 2; ++fn) {
            bfh[fn] = *(const bf16x8*)&bh_[bn + fn * 16][kk * 32 + coff];
            bfl[fn] = *(const bf16x8*)&bl[bn + fn * 16][kk * 32 + coff];
        }
        #pragma unroll
        for (int fm = 0; fm < 2; ++fm)
            #pragma unroll
            for (int fn = 0; fn < 2; ++fn) {
                acc[fm][fn] = __builtin_amdgcn_mfma_f32_16x16x32_bf16(
                    afh[fm], bfh[fn], acc[fm][fn], 0, 0, 0);
                acc[fm][fn] = __builtin_amdgcn_mfma_f32_16x16x32_bf16(
                    afh[fm], bfl[fn], acc[fm][fn], 0, 0, 0);
                acc[fm][fn] = __builtin_amdgcn_mfma_f32_16x16x32_bf16(
                    afl[fm], bfh[fn], acc[fm][fn], 0, 0, 0);
            }
    }
    int mrow = it * 64 + wm * 32 + (lane >> 4) * 4;
    int ncol = jt * 64 + wn * 32 + (lane & 15);
    #pragma unroll
    for (int fm = 0; fm < 2; ++fm)
        #pragma unroll
        for (int fn = 0; fn < 2; ++fn)
            #pragma unroll
            for (int rr = 0; rr < 4; ++rr)
                adj[((size_t)bh * kL + mrow + fm * 16 + rr) * kL + ncol + fn * 16] =
                    gelu_exact(acc[fm][fn][rr]);
}

// ---------------------------------------------------------------------------
// K3 (fused): per-row, one wave:
//  - exact 256th-smallest via ballot/popcount bisection w/ early exit
//  - threshold; logits = row @ Wg^T; softmax-3; stable top-p -> gates
//  - mask build + diag, masked row softmax, L1 renorm, bf16 adjb write
// grid = ROWS/4 blocks of 256. Lane owns j = lane*8..+7.
// ---------------------------------------------------------------------------
__global__ __launch_bounds__(256) void k_select(const float* __restrict__ adj,
        const float* __restrict__ Wg, const float* __restrict__ masks,
        ushort* __restrict__ adjb,
        float* __restrict__ spbuf, float* __restrict__ entbuf) {
    int tid = threadIdx.x;
    int wave = tid >> 6, lane = tid & 63;
    int row = blockIdx.x * 4 + wave;
    int i = row & (kL - 1);
    const float* arow = adj + (size_t)row * kL;
    int j0 = lane * 8;

    float v[8];
    {
        float4 a0 = *(const float4*)&arow[j0];
        float4 a1 = *(const float4*)&arow[j0 + 4];
        v[0] = a0.x; v[1] = a0.y; v[2] = a0.z; v[3] = a0.w;
        v[4] = a1.x; v[5] = a1.y; v[6] = a1.z; v[7] = a1.w;
    }
    unsigned key[8];
    #pragma unroll
    for (int t = 0; t < 8; ++t) {
        unsigned u = __float_as_uint(v[t]);
        key[t] = (u & 0x80000000u) ? ~u : (u | 0x80000000u);
    }

    // exact k-th smallest (k=255 0-indexed): bisection, ballot counting.
    unsigned prefix = 0;
    int cbp = 0, cin = 512;
    int bit = 31;
    while (cin > 1 && bit >= 0) {
        unsigned cand = prefix | (1u << bit);
        int c = 0;
        #pragma unroll
        for (int t = 0; t < 8; ++t)
            c += (int)__popcll(__ballot(key[t] < cand));
        if (255 < c) {
            cin = c - cbp;               // kth in [prefix, cand)
        } else {
            cin -= (c - cbp);            // kth in [cand, hi)
            prefix = cand;
            cbp = c;
        }
        --bit;
    }
    unsigned width = 1u << (bit + 1);
    unsigned kk2 = 0;
    #pragma unroll
    for (int t = 0; t < 8; ++t) {
        unsigned d = key[t] - prefix;
        if (d < width) kk2 = max(kk2, key[t]);
    }
    #pragma unroll
    for (int off = 1; off < 64; off <<= 1) kk2 = max(kk2, (unsigned)__shfl_xor((int)kk2, off));
    float thr = (kk2 & 0x80000000u) ? __uint_as_float(kk2 & 0x7fffffffu)
                                    : __uint_as_float(~kk2);

    // threshold + logits
    float l0 = 0.f, l1 = 0.f, l2 = 0.f;
    #pragma unroll
    for (int t = 0; t < 8; ++t) {
        float nv = (v[t] > thr) ? v[t] : 0.0f;
        v[t] = nv;
        int j = j0 + t;
        l0 = fmaf(nv, Wg[j], l0);
        l1 = fmaf(nv, Wg[kL + j], l1);
        l2 = fmaf(nv, Wg[2 * kL + j], l2);
    }
    #pragma unroll
    for (int off = 1; off < 64; off <<= 1) {
        l0 += __shfl_xor(l0, off);
        l1 += __shfl_xor(l1, off);
        l2 += __shfl_xor(l2, off);
    }
    // softmax-3 + stable top-p (all lanes redundantly; wave-uniform)
    float m = fmaxf(l0, fmaxf(l1, l2));
    float e0 = expf(l0 - m), e1 = expf(l1 - m), e2 = expf(l2 - m);
    float s = e0 + e1 + e2;
    float p[3] = {e0 / s, e1 / s, e2 / s};
    int o0, o1, o2;
    if (p[0] >= p[1] && p[0] >= p[2]) o0 = 0;
    else if (p[1] >= p[2]) o0 = 1;
    else o0 = 2;
    int r0 = (o0 == 0) ? 1 : 0;
    int r1 = (o0 == 2) ? 1 : 2;
    if (p[r0] >= p[r1]) { o1 = r0; o2 = r1; } else { o1 = r1; o2 = r0; }
    float sp0 = p[o0], sp1 = p[o1], sp2 = p[o2];
    float c0 = sp0, c1 = sp0 + sp1, c2 = c1 + sp2;
    bool m0 = c0 > 0.5f, m1 = c1 > 0.5f, m2 = c2 > 0.5f;
    int ti = m0 ? 0 : (m1 ? 1 : 2);
    bool mm0 = m0 && (ti != 0);
    bool mm1 = m1 && (ti != 1);
    bool mm2 = m2 && (ti != 2);
    float g[3] = {0.f, 0.f, 0.f};
    g[o0] = mm0 ? 0.f : 1.f;
    g[o1] = mm1 ? 0.f : 1.f;
    g[o2] = mm2 ? 0.f : 1.f;
    if (lane == 0) {
        spbuf[row * 3 + 0] = mm0 ? 0.f : sp0;
        spbuf[row * 3 + 1] = mm1 ? 0.f : sp1;
        spbuf[row * 3 + 2] = mm2 ? 0.f : sp2;
        entbuf[row] = p[0] * logf(p[0] + 1e-10f) +
                      p[1] * logf(p[1] + 1e-10f) +
                      p[2] * logf(p[2] + 1e-10f);
    }

    // mask build + diag, apply to thresholded values
    const float* mk0 = masks + (i * 3 + 0) * kL + j0;
    const float* mk1 = masks + (i * 3 + 1) * kL + j0;
    const float* mk2 = masks + (i * 3 + 2) * kL + j0;
    float av[8];
    #pragma unroll
    for (int half = 0; half < 2; ++half) {
        float4 v0 = *(const float4*)&mk0[half * 4];
        float4 v1 = *(const float4*)&mk1[half * 4];
        float4 v2 = *(const float4*)&mk2[half * 4];
        float mv[4];
        mv[0] = g[0] * v0.x + g[1] * v1.x + g[2] * v2.x;
        mv[1] = g[0] * v0.y + g[1] * v1.y + g[2] * v2.y;
        mv[2] = g[0] * v0.z + g[1] * v1.z + g[2] * v2.z;
        mv[3] = g[0] * v0.w + g[1] * v1.w + g[2] * v2.w;
        #pragma unroll
        for (int t = 0; t < 4; ++t) {
            int j = j0 + half * 4 + t;
            float mm = mv[t] + ((j == i) ? 1.0f : 0.0f);
            av[half * 4 + t] = v[half * 4 + t] * mm;
        }
    }
    // masked row softmax + L1 renorm
    float mx = av[0];
    #pragma unroll
    for (int t = 1; t < 8; ++t) mx = fmaxf(mx, av[t]);
    #pragma unroll
    for (int off = 1; off < 64; off <<= 1) mx = fmaxf(mx, __shfl_xor(mx, off));
    float e[8], ls = 0.f;
    #pragma unroll
    for (int t = 0; t < 8; ++t) { e[t] = expf(av[t] - mx); ls += e[t]; }
    #pragma unroll
    for (int off = 1; off < 64; off <<= 1) ls += __shfl_xor(ls, off);
    float inv = 1.0f / ls;
    float pp[8], l1s = 0.f;
    #pragma unroll
    for (int t = 0; t < 8; ++t) { pp[t] = e[t] * inv; l1s += fabsf(pp[t]); }
    #pragma unroll
    for (int off = 1; off < 64; off <<= 1) l1s += __shfl_xor(l1s, off);
    float s2 = 1.0f / fmaxf(l1s, 1e-12f);
    union { ushort u[8]; int4 vv; } pk;
    #pragma unroll
    for (int t = 0; t < 8; ++t) pk.u[t] = f2bf(pp[t] * s2);
    *(int4*)&adjb[(size_t)row * kL + j0] = pk.vv;
}

// ---------------------------------------------------------------------------
// K4 (MFMA, bf16): xp = x @ Wp^T + bp, written TRANSPOSED bf16:
// xpbT[dcol][b*L + l]. fp32->bf16 conversion in staging; transposed store
// comes free from the C-fragment layout (4 consecutive rows per lane).
// grid = (4096/64)*(512/64) = 512 blocks, 256 thr (4 waves, 2x2 of 32x32).
// ---------------------------------------------------------------------------
__global__ __launch_bounds__(256) void k_xp(const float* __restrict__ x,
        const float* __restrict__ Wp, const float* __restrict__ bp,
        ushort* __restrict__ xpbT) {
    int it = blockIdx.x >> 3, jt = blockIdx.x & 7;   // it: l-rows, jt: d-cols
    __shared__ ushort xbs[64][72];
    __shared__ ushort wbs[64][72];
    int tid = threadIdx.x;
    int r = tid >> 2, s = tid & 3;
    int lane = tid & 63, wave = tid >> 6;
    int wm = wave >> 1, wn = wave & 1;
    int am = wm * 32 + (lane & 15);
    int bn = wn * 32 + (lane & 15);
    int coff = (lane >> 4) * 8;
    f32x4 acc[2][2] = {};
    const float* xsrc = x + (size_t)(it * 64 + r) * kD + s * 16;
    const float* wsrc = Wp + (size_t)(jt * 64 + r) * kD + s * 16;
    for (int kt = 0; kt < 8; ++kt) {
        union { ushort u[16]; int4 v[2]; } px, pw;
        #pragma unroll
        for (int c4 = 0; c4 < 4; ++c4) {
            float4 fx = *(const float4*)(xsrc + kt * 64 + c4 * 4);
            float4 fw = *(const float4*)(wsrc + kt * 64 + c4 * 4);
            px.u[c4 * 4 + 0] = f2bf(fx.x); px.u[c4 * 4 + 1] = f2bf(fx.y);
            px.u[c4 * 4 + 2] = f2bf(fx.z); px.u[c4 * 4 + 3] = f2bf(fx.w);
            pw.u[c4 * 4 + 0] = f2bf(fw.x); pw.u[c4 * 4 + 1] = f2bf(fw.y);
            pw.u[c4 * 4 + 2] = f2bf(fw.z); pw.u[c4 * 4 + 3] = f2bf(fw.w);
        }
        __syncthreads();
        *(int4*)&xbs[r][s * 16] = px.v[0];
        *(int4*)&xbs[r][s * 16 + 8] = px.v[1];
        *(int4*)&wbs[r][s * 16] = pw.v[0];
        *(int4*)&wbs[r][s * 16 + 8] = pw.v[1];
        __syncthreads();
        #pragma unroll
        for (int kk = 0; kk < 2; ++kk) {
            bf16x8 af[2], bf[2];
            #pragma unroll
            for (int fm = 0; fm < 2; ++fm)
                af[fm] = *(const bf16x8*)&xbs[am + fm * 16][kk * 32 + coff];
            #pragma unroll
            for (int fn = 0; fn < 2; ++fn)
                bf[fn] = *(const bf16x8*)&wbs[bn + fn * 16][kk * 32 + coff];
            #pragma unroll
            for (int fm = 0; fm < 2; ++fm)
                #pragma unroll
                for (int fn = 0; fn < 2; ++fn)
                    acc[fm][fn] = __builtin_amdgcn_mfma_f32_16x16x32_bf16(
                        af[fm], bf[fn], acc[fm][fn], 0, 0, 0);
        }
    }
    // epilogue: add bias, store transposed (4 consecutive l per lane)
    #pragma unroll
    for (int fn = 0; fn < 2; ++fn) {
        int dcol = jt * 64 + wn * 32 + (lane & 15) + fn * 16;
        float bpv = bp[dcol];
        #pragma unroll
        for (int fm = 0; fm < 2; ++fm) {
            int l0 = it * 64 + wm * 32 + fm * 16 + (lane >> 4) * 4;
            union { ushort u[4]; uint2 v; } pk;
            #pragma unroll
            for (int rr = 0; rr < 4; ++rr)
                pk.u[rr] = f2bf(acc[fm][fn][rr] + bpv);
            *(uint2*)&xpbT[(size_t)dcol * (size_t)(kB * kL) + l0] = pk.v;
        }
    }
}

// ---------------------------------------------------------------------------
// K6 (MFMA): out[b, i, h*64+d] = sum_j adjb[bh,i,j] * xpbT[h*64+d][b*512+j]
// ---------------------------------------------------------------------------
__global__ __launch_bounds__(256) void k_out(const ushort* __restrict__ adjb,
        const ushort* __restrict__ xpbT, float* __restrict__ out) {
    int blk = blockIdx.x;
    int bh = blk >> 3, it = blk & 7;
    int b = bh >> 3, h = bh & 7;
    __shared__ ushort as_[64][72];
    __shared__ ushort bs_[64][72];
    int tid = threadIdx.x;
    int lane = tid & 63, wave = tid >> 6;
    int wm = wave >> 1, wn = wave & 1;
    int r = tid >> 2, s = tid & 3;
    const ushort* aG = adjb + ((size_t)(bh * kL + it * 64 + r)) * kL + s * 16;
    const ushort* bG = xpbT + ((size_t)(h * kDH + r)) * (size_t)(kB * kL) + b * kL + s * 16;
    f32x4 acc[2][2] = {};
    int am = wm * 32 + (lane & 15);
    int bn = wn * 32 + (lane & 15);
    int coff = (lane >> 4) * 8;
    for (int kt = 0; kt < 8; ++kt) {
        int4 a0 = *(const int4*)(aG + kt * 64);
        int4 a1 = *(const int4*)(aG + kt * 64 + 8);
        int4 b0 = *(const int4*)(bG + kt * 64);
        int4 b1 = *(const int4*)(bG + kt * 64 + 8);
        __syncthreads();
        *(int4*)&as_[r][s * 16] = a0;
        *(int4*)&as_[r][s * 16 + 8] = a1;
        *(int4*)&bs_[r][s * 16] = b0;
        *(int4*)&bs_[r][s * 16 + 8] = b1;
        __syncthreads();
        #pragma unroll
        for (int kk = 0; kk < 2; ++kk) {
            bf16x8 af[2], bf[2];
            #pragma unroll
            for (int fm = 0; fm < 2; ++fm)
                af[fm] = *(const bf16x8*)&as_[am + fm * 16][kk * 32 + coff];
            #pragma unroll
            for (int fn = 0; fn < 2; ++fn)
                bf[fn] = *(const bf16x8*)&bs_[bn + fn * 16][kk * 32 + coff];
            #pragma unroll
            for (int fm = 0; fm < 2; ++fm)
                #pragma unroll
                for (int fn = 0; fn < 2; ++fn)
                    acc[fm][fn] = __builtin_amdgcn_mfma_f32_16x16x32_bf16(
                        af[fm], bf[fn], acc[fm][fn], 0, 0, 0);
        }
    }
    int mrow = it * 64 + wm * 32 + (lane >> 4) * 4;
    int ncol = h * kDH + wn * 32 + (lane & 15);
    #pragma unroll
    for (int fm = 0; fm < 2; ++fm)
        #pragma unroll
        for (int fn = 0; fn < 2; ++fn)
            #pragma unroll
            for (int rr = 0; rr < 4; ++rr)
                out[((size_t)b * kL + mrow + fm * 16 + rr) * kD + ncol + fn * 16] =
                    acc[fm][fn][rr];
}

// ---------------------------------------------------------------------------
// K7: finalize loss (single block, deterministic reductions)
// ---------------------------------------------------------------------------
__global__ __launch_bounds__(1024) void k_loss(const float* __restrict__ spbuf,
        const float* __restrict__ entbuf, float* __restrict__ out_loss) {
    __shared__ float imps[kL * 3];
    __shared__ float red[1024];
    int tid = threadIdx.x;
    for (int idx = tid; idx < kL * 3; idx += 1024) {
        float s = 0.f;
        for (int bh = 0; bh < kBH; ++bh)
            s += spbuf[bh * kL * 3 + idx];
        imps[idx] = s;
    }
    float es = 0.f;
    for (int idx = tid; idx < kROWS; idx += 1024) es += entbuf[idx];
    red[tid] = es;
    __syncthreads();
    for (int s = 512; s > 0; s >>= 1) {
        if (tid < s) red[tid] += red[tid + s];
        __syncthreads();
    }
    float ent_total = red[0];
    __syncthreads();
    float ms = 0.f;
    for (int idx = tid; idx < kL * 3; idx += 1024) ms += imps[idx];
    red[tid] = ms;
    __syncthreads();
    for (int s = 512; s > 0; s >>= 1) {
        if (tid < s) red[tid] += red[tid + s];
        __syncthreads();
    }
    float mean = red[0] / (float)(kL * 3);
    __syncthreads();
    float vs = 0.f;
    for (int idx = tid; idx < kL * 3; idx += 1024) {
        float d = imps[idx] - mean;
        vs += d * d;
    }
    red[tid] = vs;
    __syncthreads();
    for (int s = 512; s > 0; s >>= 1) {
        if (tid < s) red[tid] += red[tid + s];
        __syncthreads();
    }
    if (tid == 0) {
        float var = red[0] / (float)(kL * 3 - 1);
        float loss_imp = var / (mean * mean + 1e-10f);
        float loss_dyn = -ent_total / (float)(kBH * 3);
        out_loss[0] = loss_imp + 0.1f * loss_dyn;
    }
}

// ---------------------------------------------------------------------------
extern "C" void kernel_launch(void* const* d_in, const int* in_sizes, int n_in,
                              void* d_out, int out_size, void* d_ws, size_t ws_size,
                              hipStream_t stream) {
    const float* x     = (const float*)d_in[0];
    const float* masks = (const float*)d_in[1];
    const float* W1    = (const float*)d_in[2];
    const float* b1    = (const float*)d_in[3];
    const float* W2    = (const float*)d_in[4];
    const float* b2    = (const float*)d_in[5];
    const float* Wg    = (const float*)d_in[6];
    const float* Wp    = (const float*)d_in[7];
    const float* bp    = (const float*)d_in[8];
    float* out = (float*)d_out;
    float* ws  = (float*)d_ws;

    // workspace layout (float units). adjb overlays q,k (dead after k_adj;
    // stream order serializes k_adj -> k_select).
    float*  adj   = ws;                          // [0, 16777216)
    float*  q     = ws + 16777216;               // [16777216, 18874368)
    float*  k     = ws + 18874368;               // [18874368, 20971520)
    ushort* adjb  = (ushort*)(ws + 16777216);    // [16777216, 25165824) f-units
    ushort* xpbT  = (ushort*)(ws + 25165824);    // [25165824, 26214400) f-units
    float*  spbuf = ws + 26214400;               // 98,304
    float*  entbuf= ws + 26312704;               // 32,768

    k_qk<<<512, 256, 0, stream>>>(x, W1, b1, W2, b2, q, k);
    k_adj<<<kBH * 64, 256, 0, stream>>>(q, k, adj);
    k_select<<<kROWS / 4, 256, 0, stream>>>(adj, Wg, masks, adjb, spbuf, entbuf);
    k_xp<<<512, 256, 0, stream>>>(x, Wp, bp, xpbT);
    k_out<<<512, 256, 0, stream>>>(adjb, xpbT, out);
    k_loss<<<1, 1024, 0, stream>>>(spbuf, entbuf, out + (size_t)kB * kL * kD);
}